// Round 1
// baseline (1012.440 us; speedup 1.0000x reference)
//
#include <hip/hip_runtime.h>
#include <hip/hip_bf16.h>
#include <math.h>

typedef __bf16 bf16_t;
typedef __bf16 bf16x8 __attribute__((ext_vector_type(8)));
typedef float  f32x4  __attribute__((ext_vector_type(4)));

#define B_   2
#define S_   2048
#define D_   4096
#define NH_  32
#define NKV_ 8
#define HD_  128
#define NREP_ 4

static __device__ __forceinline__ void gload_lds16(const bf16_t* g, bf16_t* l) {
  __builtin_amdgcn_global_load_lds(
      (const __attribute__((address_space(1))) void*)g,
      (__attribute__((address_space(3))) void*)l, 16, 0, 0);
}

// ---------------- elementwise f32 -> bf16 convert (vectorized) ----------------
__global__ void convert_f32_bf16(const float* __restrict__ in, bf16_t* __restrict__ out,
                                 size_t n8) {
  size_t i = (size_t)blockIdx.x * blockDim.x + threadIdx.x;
  if (i >= n8) return;
  f32x4 a = *(const f32x4*)(in + i * 8);
  f32x4 b = *(const f32x4*)(in + i * 8 + 4);
  bf16x8 o;
  o[0] = (bf16_t)a[0]; o[1] = (bf16_t)a[1]; o[2] = (bf16_t)a[2]; o[3] = (bf16_t)a[3];
  o[4] = (bf16_t)b[0]; o[5] = (bf16_t)b[1]; o[6] = (bf16_t)b[2]; o[7] = (bf16_t)b[3];
  *(bf16x8*)(out + i * 8) = o;
}

// ---------------- transpose + convert: in (R,C) f32 -> out (C,R) bf16 ----------------
__global__ void transpose_convert(const float* __restrict__ in, bf16_t* __restrict__ out,
                                  int R, int C) {
  __shared__ float tile[32][33];
  const int c0 = blockIdx.x * 32, r0 = blockIdx.y * 32;
  const int tc = threadIdx.x & 31, tr = threadIdx.x >> 5;  // tr in 0..7
#pragma unroll
  for (int i = 0; i < 4; i++) {
    int r = tr + i * 8;
    tile[r][tc] = in[(size_t)(r0 + r) * C + c0 + tc];
  }
  __syncthreads();
#pragma unroll
  for (int i = 0; i < 4; i++) {
    int r = tr + i * 8;  // row of OUT tile = col of in
    out[(size_t)(c0 + r) * R + r0 + tc] = (bf16_t)tile[tc][r];
  }
}

// ---------------- transpose V: (B,S,NKV,HD) bf16 -> (B,NKV,HD,S) bf16 ----------------
__global__ void transpose_v(const bf16_t* __restrict__ in, bf16_t* __restrict__ out) {
  __shared__ bf16_t tile[32][33];
  const int t0 = blockIdx.x * 32, d0 = blockIdx.y * 32;
  const int bg = blockIdx.z, b = bg / NKV_, g = bg % NKV_;
  const bf16_t* ibase = in + ((size_t)b * S_ * NKV_ + g) * HD_;
  bf16_t* obase = out + ((size_t)b * NKV_ + g) * (size_t)HD_ * S_;
  const int tc = threadIdx.x & 31, tr = threadIdx.x >> 5;
#pragma unroll
  for (int i = 0; i < 4; i++) {
    int t = t0 + tr + i * 8;
    tile[tr + i * 8][tc] = ibase[(size_t)t * NKV_ * HD_ + d0 + tc];
  }
  __syncthreads();
#pragma unroll
  for (int i = 0; i < 4; i++) {
    int d = d0 + tr + i * 8;
    obase[(size_t)d * S_ + t0 + tc] = tile[tc][tr + i * 8];
  }
}

// ---------------- RoPE in-place on bf16 (B,S,nh,HD) ----------------
__global__ void rope_inplace(bf16_t* __restrict__ x, const float* __restrict__ cosT,
                             const float* __restrict__ sinT, int nheads, size_t nchunks) {
  size_t i = (size_t)blockIdx.x * blockDim.x + threadIdx.x;
  if (i >= nchunks) return;
  const int d8 = (int)(i & 15);          // 16 chunks of 8 elems per head-row (HD=128)
  const size_t row = i >> 4;             // (b*S + s)*nheads + h
  const int s = (int)((row / nheads) % S_);
  bf16x8 v = *(bf16x8*)(x + i * 8);
  f32x4 c  = *(const f32x4*)(cosT + (size_t)s * 64 + d8 * 4);
  f32x4 sn = *(const f32x4*)(sinT + (size_t)s * 64 + d8 * 4);
  bf16x8 o;
#pragma unroll
  for (int j = 0; j < 4; j++) {
    float re = (float)v[2 * j], im = (float)v[2 * j + 1];
    o[2 * j]     = (bf16_t)(re * c[j] - im * sn[j]);
    o[2 * j + 1] = (bf16_t)(re * sn[j] + im * c[j]);
  }
  *(bf16x8*)(x + i * 8) = o;
}

// ---------------- NT GEMM: C(M,N) = A(M,K) @ Bt(N,K)^T, bf16 in, OutT out ----------------
template <typename OutT>
__global__ __launch_bounds__(256) void gemm_nt(const bf16_t* __restrict__ A,
                                               const bf16_t* __restrict__ Bt,
                                               OutT* __restrict__ C, int M, int N, int K) {
  __shared__ __align__(16) bf16_t As[128][32];
  __shared__ __align__(16) bf16_t Bs[128][32];
  const int t = threadIdx.x, w = t >> 6, l = t & 63;
  const int wm = w >> 1, wn = w & 1;
  const int m0 = blockIdx.y * 128, n0 = blockIdx.x * 128;
  const int lr = l & 15, lg = l >> 4;
  const int srow = l >> 2, scol = (l & 3) * 8;

  f32x4 zero = {0.f, 0.f, 0.f, 0.f};
  f32x4 acc[4][4];
#pragma unroll
  for (int i = 0; i < 4; i++)
#pragma unroll
    for (int j = 0; j < 4; j++) acc[i][j] = zero;

  const size_t arow = (size_t)(m0 + w * 16 + srow) * K + scol;
  const size_t brow = (size_t)(n0 + w * 16 + srow) * K + scol;

  for (int k0 = 0; k0 < K; k0 += 32) {
#pragma unroll
    for (int j = 0; j < 2; j++) {
      gload_lds16(A + arow + (size_t)j * 64 * K + k0, &As[j * 64 + w * 16][0]);
      gload_lds16(Bt + brow + (size_t)j * 64 * K + k0, &Bs[j * 64 + w * 16][0]);
    }
    __syncthreads();
    bf16x8 af[4], bfr[4];
#pragma unroll
    for (int m = 0; m < 4; m++) af[m] = *(const bf16x8*)&As[wm * 64 + m * 16 + lr][lg * 8];
#pragma unroll
    for (int n = 0; n < 4; n++) bfr[n] = *(const bf16x8*)&Bs[wn * 64 + n * 16 + lr][lg * 8];
#pragma unroll
    for (int m = 0; m < 4; m++)
#pragma unroll
      for (int n = 0; n < 4; n++)
        acc[m][n] = __builtin_amdgcn_mfma_f32_16x16x32_bf16(af[m], bfr[n], acc[m][n], 0, 0, 0);
    __syncthreads();
  }
#pragma unroll
  for (int m = 0; m < 4; m++)
#pragma unroll
    for (int n = 0; n < 4; n++) {
      const int row = m0 + wm * 64 + m * 16 + lg * 4;
      const int col = n0 + wn * 64 + n * 16 + lr;
#pragma unroll
      for (int r = 0; r < 4; r++) C[(size_t)(row + r) * N + col] = (OutT)acc[m][n][r];
    }
}

// ---------------- flash attention (causal, GQA) ----------------
// Q:(B,S,NH,HD) K:(B,S,NKV,HD) Vt:(B,NKV,HD,S) O:(B,S,NH,HD), all bf16
#define QBLK 64
#define KVBLK 64
__global__ __launch_bounds__(256) void flash_attn(const bf16_t* __restrict__ Q,
                                                  const bf16_t* __restrict__ Kg,
                                                  const bf16_t* __restrict__ Vt,
                                                  bf16_t* __restrict__ O) {
  const int qb = blockIdx.x, h = blockIdx.y, b = blockIdx.z;
  const int g = h >> 2;  // NREP=4
  const int t = threadIdx.x, w = t >> 6, l = t & 63;
  const int lr = l & 15, lg = l >> 4;
  __shared__ __align__(16) bf16_t Qs[QBLK][HD_ + 8];
  __shared__ __align__(16) bf16_t Ks[KVBLK][HD_ + 8];
  __shared__ __align__(16) bf16_t Vs[HD_][KVBLK + 8];
  __shared__ __align__(16) bf16_t Ps[4][16][KVBLK + 8];
  const int q0 = qb * QBLK;
  const float scale = 0.08838834764831845f;

  // load Q tile
  {
    const int r = t >> 4, c = (t & 15) * 8;
#pragma unroll
    for (int i = 0; i < 4; i++)
      *(bf16x8*)&Qs[i * 16 + r][c] =
          *(const bf16x8*)&Q[(((size_t)b * S_ + q0 + i * 16 + r) * NH_ + h) * HD_ + c];
  }

  float mrun[4], lrun[4];
  f32x4 acc[8];
  f32x4 zero = {0.f, 0.f, 0.f, 0.f};
#pragma unroll
  for (int r = 0; r < 4; r++) { mrun[r] = -INFINITY; lrun[r] = 0.f; }
#pragma unroll
  for (int d = 0; d < 8; d++) acc[d] = zero;

  for (int kb = 0; kb <= qb; kb++) {
    const int t0 = kb * KVBLK;
    __syncthreads();  // all waves done reading previous K/V
    {
      const int r = t >> 4, c = (t & 15) * 8;
#pragma unroll
      for (int i = 0; i < 4; i++)
        *(bf16x8*)&Ks[i * 16 + r][c] =
            *(const bf16x8*)&Kg[(((size_t)b * S_ + t0 + i * 16 + r) * NKV_ + g) * HD_ + c];
    }
    {
      const int d = t >> 3, c = (t & 7) * 8;
#pragma unroll
      for (int i = 0; i < 4; i++)
        *(bf16x8*)&Vs[i * 32 + d][c] =
            *(const bf16x8*)&Vt[(((size_t)b * NKV_ + g) * HD_ + i * 32 + d) * S_ + t0 + c];
    }
    __syncthreads();

    // S = Q_w @ K^T   (wave w owns q rows w*16 .. w*16+15)
    f32x4 sf[4];
#pragma unroll
    for (int n = 0; n < 4; n++) sf[n] = zero;
#pragma unroll
    for (int kk = 0; kk < 4; kk++) {
      bf16x8 aq = *(const bf16x8*)&Qs[w * 16 + lr][kk * 32 + lg * 8];
#pragma unroll
      for (int n = 0; n < 4; n++) {
        bf16x8 bk = *(const bf16x8*)&Ks[n * 16 + lr][kk * 32 + lg * 8];
        sf[n] = __builtin_amdgcn_mfma_f32_16x16x32_bf16(aq, bk, sf[n], 0, 0, 0);
      }
    }

    const bool diag = (kb == qb);
    float pv[4][4];
#pragma unroll
    for (int r = 0; r < 4; r++) {
      const int qrow = q0 + w * 16 + lg * 4 + r;
      float mx = -INFINITY;
#pragma unroll
      for (int n = 0; n < 4; n++) {
        float xv = sf[n][r] * scale;
        if (diag && (t0 + n * 16 + lr > qrow)) xv = -INFINITY;
        pv[n][r] = xv;
        mx = fmaxf(mx, xv);
      }
      mx = fmaxf(mx, __shfl_xor(mx, 1));
      mx = fmaxf(mx, __shfl_xor(mx, 2));
      mx = fmaxf(mx, __shfl_xor(mx, 4));
      mx = fmaxf(mx, __shfl_xor(mx, 8));
      const float mnew = fmaxf(mrun[r], mx);
      const float corr = __expf(mrun[r] - mnew);
      float sum = 0.f;
#pragma unroll
      for (int n = 0; n < 4; n++) {
        float p = __expf(pv[n][r] - mnew);
        pv[n][r] = p;
        sum += p;
      }
      sum += __shfl_xor(sum, 1);
      sum += __shfl_xor(sum, 2);
      sum += __shfl_xor(sum, 4);
      sum += __shfl_xor(sum, 8);
      lrun[r] = lrun[r] * corr + sum;
      mrun[r] = mnew;
#pragma unroll
      for (int d = 0; d < 8; d++) acc[d][r] *= corr;
    }

    // P -> LDS (per-wave region), then PV via MFMA
#pragma unroll
    for (int r = 0; r < 4; r++)
#pragma unroll
      for (int n = 0; n < 4; n++) Ps[w][lg * 4 + r][n * 16 + lr] = (bf16_t)pv[n][r];

#pragma unroll
    for (int kk = 0; kk < 2; kk++) {
      bf16x8 ap = *(const bf16x8*)&Ps[w][lr][kk * 32 + lg * 8];
#pragma unroll
      for (int d = 0; d < 8; d++) {
        bf16x8 bv = *(const bf16x8*)&Vs[d * 16 + lr][kk * 32 + lg * 8];
        acc[d] = __builtin_amdgcn_mfma_f32_16x16x32_bf16(ap, bv, acc[d], 0, 0, 0);
      }
    }
  }

  // epilogue: O = acc / l
#pragma unroll
  for (int r = 0; r < 4; r++) {
    const int q = q0 + w * 16 + lg * 4 + r;
    const float inv = 1.f / lrun[r];
#pragma unroll
    for (int d = 0; d < 8; d++)
      O[(((size_t)b * S_ + q) * NH_ + h) * HD_ + d * 16 + lr] = (bf16_t)(acc[d][r] * inv);
  }
}

extern "C" void kernel_launch(void* const* d_in, const int* in_sizes, int n_in,
                              void* d_out, int out_size, void* d_ws, size_t ws_size,
                              hipStream_t stream) {
  const float* x    = (const float*)d_in[0];
  const float* fcos = (const float*)d_in[1];
  const float* fsin = (const float*)d_in[2];
  const float* wq   = (const float*)d_in[3];
  const float* wk   = (const float*)d_in[4];
  const float* wv   = (const float*)d_in[5];
  const float* wo   = (const float*)d_in[6];
  float* out = (float*)d_out;

  char* ws = (char*)d_ws;
  bf16_t* x_bf  = (bf16_t*)(ws);                    // 33.5 MB
  bf16_t* wt    = (bf16_t*)(ws + 33554432);         // 33.5 MB (wq^T, later wo^T)
  bf16_t* wkt   = (bf16_t*)(ws + 67108864);         // 8.4 MB
  bf16_t* wvt   = (bf16_t*)(ws + 75497472);         // 8.4 MB
  bf16_t* q_bf  = (bf16_t*)(ws + 83886080);         // 33.5 MB
  bf16_t* k_bf  = (bf16_t*)(ws + 117440512);        // 8.4 MB
  bf16_t* xv_bf = (bf16_t*)(ws + 125829120);        // 8.4 MB
  bf16_t* vt    = (bf16_t*)(ws + 134217728);        // 8.4 MB
  bf16_t* attn  = (bf16_t*)(ws + 142606336);        // 33.5 MB  (end ~176 MB)

  // 1. convert x to bf16
  convert_f32_bf16<<<8192, 256, 0, stream>>>(x, x_bf, (size_t)2097152);
  // 2. transpose+convert weights (to (N,K) bf16)
  transpose_convert<<<dim3(128, 128), 256, 0, stream>>>(wq, wt, 4096, 4096);
  transpose_convert<<<dim3(32, 128), 256, 0, stream>>>(wk, wkt, 4096, 1024);
  transpose_convert<<<dim3(32, 128), 256, 0, stream>>>(wv, wvt, 4096, 1024);
  // 3. QKV projections (bf16 out)
  gemm_nt<bf16_t><<<dim3(32, 32), 256, 0, stream>>>(x_bf, wt, q_bf, 4096, 4096, 4096);
  gemm_nt<bf16_t><<<dim3(8, 32), 256, 0, stream>>>(x_bf, wkt, k_bf, 4096, 1024, 4096);
  gemm_nt<bf16_t><<<dim3(8, 32), 256, 0, stream>>>(x_bf, wvt, xv_bf, 4096, 1024, 4096);
  // 4. RoPE in-place on q,k
  rope_inplace<<<8192, 256, 0, stream>>>(q_bf, fcos, fsin, NH_, (size_t)2097152);
  rope_inplace<<<2048, 256, 0, stream>>>(k_bf, fcos, fsin, NKV_, (size_t)524288);
  // 5. V -> (B,NKV,HD,S)
  transpose_v<<<dim3(64, 4, 16), 256, 0, stream>>>(xv_bf, vt);
  // 6. wo^T into the big weight slot (wq^T no longer needed)
  transpose_convert<<<dim3(128, 128), 256, 0, stream>>>(wo, wt, 4096, 4096);
  // 7. flash attention
  flash_attn<<<dim3(32, 32, 2), 256, 0, stream>>>(q_bf, k_bf, vt, attn);
  // 8. output projection (f32 out)
  gemm_nt<float><<<dim3(32, 32), 256, 0, stream>>>(attn, wt, out, 4096, 4096, 4096);
}

// Round 2
// 962.686 us; speedup vs baseline: 1.0517x; 1.0517x over previous
//
#include <hip/hip_runtime.h>
#include <hip/hip_bf16.h>
#include <math.h>

typedef __bf16 bf16_t;
typedef __bf16 bf16x8 __attribute__((ext_vector_type(8)));
typedef float  f32x4  __attribute__((ext_vector_type(4)));

#define B_   2
#define S_   2048
#define D_   4096
#define NH_  32
#define NKV_ 8
#define HD_  128
#define NREP_ 4

static __device__ __forceinline__ void gload_lds16(const bf16_t* g, bf16_t* l) {
  __builtin_amdgcn_global_load_lds(
      (const __attribute__((address_space(1))) void*)g,
      (__attribute__((address_space(3))) void*)l, 16, 0, 0);
}

// ---------------- elementwise f32 -> bf16 convert (vectorized) ----------------
__global__ void convert_f32_bf16(const float* __restrict__ in, bf16_t* __restrict__ out,
                                 size_t n8) {
  size_t i = (size_t)blockIdx.x * blockDim.x + threadIdx.x;
  if (i >= n8) return;
  f32x4 a = *(const f32x4*)(in + i * 8);
  f32x4 b = *(const f32x4*)(in + i * 8 + 4);
  bf16x8 o;
  o[0] = (bf16_t)a[0]; o[1] = (bf16_t)a[1]; o[2] = (bf16_t)a[2]; o[3] = (bf16_t)a[3];
  o[4] = (bf16_t)b[0]; o[5] = (bf16_t)b[1]; o[6] = (bf16_t)b[2]; o[7] = (bf16_t)b[3];
  *(bf16x8*)(out + i * 8) = o;
}

// ---------------- transpose + convert: in (R,C) f32 -> out (C,R) bf16 ----------------
__global__ void transpose_convert(const float* __restrict__ in, bf16_t* __restrict__ out,
                                  int R, int C) {
  __shared__ float tile[32][33];
  const int c0 = blockIdx.x * 32, r0 = blockIdx.y * 32;
  const int tc = threadIdx.x & 31, tr = threadIdx.x >> 5;  // tr in 0..7
#pragma unroll
  for (int i = 0; i < 4; i++) {
    int r = tr + i * 8;
    tile[r][tc] = in[(size_t)(r0 + r) * C + c0 + tc];
  }
  __syncthreads();
#pragma unroll
  for (int i = 0; i < 4; i++) {
    int r = tr + i * 8;  // row of OUT tile = col of in
    out[(size_t)(c0 + r) * R + r0 + tc] = (bf16_t)tile[tc][r];
  }
}

// ---------------- transpose V: (B,S,NKV,HD) bf16 -> (B,NKV,HD,S) bf16 ----------------
__global__ void transpose_v(const bf16_t* __restrict__ in, bf16_t* __restrict__ out) {
  __shared__ bf16_t tile[32][33];
  const int t0 = blockIdx.x * 32, d0 = blockIdx.y * 32;
  const int bg = blockIdx.z, b = bg / NKV_, g = bg % NKV_;
  const bf16_t* ibase = in + ((size_t)b * S_ * NKV_ + g) * HD_;
  bf16_t* obase = out + ((size_t)b * NKV_ + g) * (size_t)HD_ * S_;
  const int tc = threadIdx.x & 31, tr = threadIdx.x >> 5;
#pragma unroll
  for (int i = 0; i < 4; i++) {
    int t = t0 + tr + i * 8;
    tile[tr + i * 8][tc] = ibase[(size_t)t * NKV_ * HD_ + d0 + tc];
  }
  __syncthreads();
#pragma unroll
  for (int i = 0; i < 4; i++) {
    int d = d0 + tr + i * 8;
    obase[(size_t)d * S_ + t0 + tc] = tile[tc][tr + i * 8];
  }
}

// ---------------- RoPE in-place on bf16 (B,S,nh,HD) ----------------
__global__ void rope_inplace(bf16_t* __restrict__ x, const float* __restrict__ cosT,
                             const float* __restrict__ sinT, int nheads, size_t nchunks) {
  size_t i = (size_t)blockIdx.x * blockDim.x + threadIdx.x;
  if (i >= nchunks) return;
  const int d8 = (int)(i & 15);          // 16 chunks of 8 elems per head-row (HD=128)
  const size_t row = i >> 4;             // (b*S + s)*nheads + h
  const int s = (int)((row / nheads) % S_);
  bf16x8 v = *(bf16x8*)(x + i * 8);
  f32x4 c  = *(const f32x4*)(cosT + (size_t)s * 64 + d8 * 4);
  f32x4 sn = *(const f32x4*)(sinT + (size_t)s * 64 + d8 * 4);
  bf16x8 o;
#pragma unroll
  for (int j = 0; j < 4; j++) {
    float re = (float)v[2 * j], im = (float)v[2 * j + 1];
    o[2 * j]     = (bf16_t)(re * c[j] - im * sn[j]);
    o[2 * j + 1] = (bf16_t)(re * sn[j] + im * c[j]);
  }
  *(bf16x8*)(x + i * 8) = o;
}

// ---------------- NT GEMM: C(M,N) = A(M,K) @ Bt(N,K)^T, bf16 in, OutT out ----------------
template <typename OutT>
__global__ __launch_bounds__(256) void gemm_nt(const bf16_t* __restrict__ A,
                                               const bf16_t* __restrict__ Bt,
                                               OutT* __restrict__ C, int M, int N, int K) {
  __shared__ __align__(16) bf16_t As[128][32];
  __shared__ __align__(16) bf16_t Bs[128][32];
  const int t = threadIdx.x, w = t >> 6, l = t & 63;
  const int wm = w >> 1, wn = w & 1;
  const int m0 = blockIdx.y * 128, n0 = blockIdx.x * 128;
  const int lr = l & 15, lg = l >> 4;
  const int srow = l >> 2, scol = (l & 3) * 8;

  f32x4 zero = {0.f, 0.f, 0.f, 0.f};
  f32x4 acc[4][4];
#pragma unroll
  for (int i = 0; i < 4; i++)
#pragma unroll
    for (int j = 0; j < 4; j++) acc[i][j] = zero;

  const size_t arow = (size_t)(m0 + w * 16 + srow) * K + scol;
  const size_t brow = (size_t)(n0 + w * 16 + srow) * K + scol;

  for (int k0 = 0; k0 < K; k0 += 32) {
#pragma unroll
    for (int j = 0; j < 2; j++) {
      gload_lds16(A + arow + (size_t)j * 64 * K + k0, &As[j * 64 + w * 16][0]);
      gload_lds16(Bt + brow + (size_t)j * 64 * K + k0, &Bs[j * 64 + w * 16][0]);
    }
    __syncthreads();
    bf16x8 af[4], bfr[4];
#pragma unroll
    for (int m = 0; m < 4; m++) af[m] = *(const bf16x8*)&As[wm * 64 + m * 16 + lr][lg * 8];
#pragma unroll
    for (int n = 0; n < 4; n++) bfr[n] = *(const bf16x8*)&Bs[wn * 64 + n * 16 + lr][lg * 8];
#pragma unroll
    for (int m = 0; m < 4; m++)
#pragma unroll
      for (int n = 0; n < 4; n++)
        acc[m][n] = __builtin_amdgcn_mfma_f32_16x16x32_bf16(af[m], bfr[n], acc[m][n], 0, 0, 0);
    __syncthreads();
  }
#pragma unroll
  for (int m = 0; m < 4; m++)
#pragma unroll
    for (int n = 0; n < 4; n++) {
      const int row = m0 + wm * 64 + m * 16 + lg * 4;
      const int col = n0 + wn * 64 + n * 16 + lr;
#pragma unroll
      for (int r = 0; r < 4; r++) C[(size_t)(row + r) * N + col] = (OutT)acc[m][n][r];
    }
}

// ---------------- flash attention v2 (causal, GQA) ----------------
// Q:(B,S,NH,HD) K:(B,S,NKV,HD) Vt:(B,NKV,HD,S) O:(B,S,NH,HD), all bf16
// 8 waves x 32 q-rows = QBLK 256 per block; KVBLK 64.
// Q in registers (scale folded); K/V/P in XOR-swizzled LDS (byte ^= (row&7)<<4).
#define QBLK 256
#define KVBLK 64
__global__ __launch_bounds__(512, 2) void flash_attn2(const bf16_t* __restrict__ Q,
                                                      const bf16_t* __restrict__ Kg,
                                                      const bf16_t* __restrict__ Vt,
                                                      bf16_t* __restrict__ O) {
  const int qb = (int)gridDim.x - 1 - (int)blockIdx.x;  // big blocks first
  const int h = blockIdx.y, b = blockIdx.z;
  const int g = h >> 2;  // NREP=4
  const int t = threadIdx.x, w = t >> 6, l = t & 63;
  const int lr = l & 15, lg = l >> 4;
  const int q0 = qb * QBLK;
  const int wq = q0 + w * 32;  // this wave's first q row

  __shared__ __align__(16) char lds[65536];
  char* Ks = lds;                       // [64][128] bf16, 256B rows, swizzled
  char* Vs = lds + 16384;               // [128][64] bf16, 128B rows, swizzled (V^T tile)
  char* Ps = lds + 32768 + w * 4096;    // per-wave [32][64] bf16, 128B rows, swizzled

  const float scale = 0.08838834764831845f;

  // Q -> registers, scale folded in
  bf16x8 qreg[2][4];
#pragma unroll
  for (int qt = 0; qt < 2; qt++)
#pragma unroll
    for (int kk = 0; kk < 4; kk++) {
      bf16x8 v = *(const bf16x8*)&Q[(((size_t)b * S_ + wq + qt * 16 + lr) * NH_ + h) * HD_ +
                                    kk * 32 + lg * 8];
#pragma unroll
      for (int j = 0; j < 8; j++) v[j] = (bf16_t)((float)v[j] * scale);
      qreg[qt][kk] = v;
    }

  float mrun[2][4], lrun[2][4];
  f32x4 acc[2][8];
  const f32x4 zero = {0.f, 0.f, 0.f, 0.f};
#pragma unroll
  for (int qt = 0; qt < 2; qt++)
#pragma unroll
    for (int r = 0; r < 4; r++) { mrun[qt][r] = -INFINITY; lrun[qt][r] = 0.f; }
#pragma unroll
  for (int qt = 0; qt < 2; qt++)
#pragma unroll
    for (int d = 0; d < 8; d++) acc[qt][d] = zero;

  const int nkb = (q0 + QBLK) / KVBLK;
  const int xmask = (lr & 7) << 4;  // row&7 == lr&7 for all b128 read rows

  for (int kb = 0; kb < nkb; kb++) {
    const int t0 = kb * KVBLK;
    __syncthreads();  // previous tile's readers done
    // ---- stage K [64][128] ----
#pragma unroll
    for (int i = 0; i < 2; i++) {
      const int c = t + i * 512;
      const int row = c >> 4, sl = c & 15;
      bf16x8 kv = *(const bf16x8*)&Kg[(((size_t)b * S_ + t0 + row) * NKV_ + g) * HD_ + sl * 8];
      *(bf16x8*)(Ks + row * 256 + ((sl * 16) ^ ((row & 7) << 4))) = kv;
    }
    // ---- stage V^T [128][64] ----
#pragma unroll
    for (int i = 0; i < 2; i++) {
      const int c = t + i * 512;
      const int row = c >> 3, sl = c & 7;
      bf16x8 vv = *(const bf16x8*)&Vt[(((size_t)b * NKV_ + g) * HD_ + row) * S_ + t0 + sl * 8];
      *(bf16x8*)(Vs + row * 128 + ((sl * 16) ^ ((row & 7) << 4))) = vv;
    }
    __syncthreads();

    if (t0 > wq + 31) continue;  // causal: wave has no work this tile (t0 <= wq when active)

    // ---- S = Q @ K^T ----
    f32x4 sf[2][4];
#pragma unroll
    for (int qt = 0; qt < 2; qt++)
#pragma unroll
      for (int n = 0; n < 4; n++) sf[qt][n] = zero;
#pragma unroll
    for (int kk = 0; kk < 4; kk++) {
      const int colb = ((kk * 32 + lg * 8) * 2) ^ xmask;
#pragma unroll
      for (int n = 0; n < 4; n++) {
        const bf16x8 bk = *(const bf16x8*)(Ks + (n * 16 + lr) * 256 + colb);
        sf[0][n] = __builtin_amdgcn_mfma_f32_16x16x32_bf16(qreg[0][kk], bk, sf[0][n], 0, 0, 0);
        sf[1][n] = __builtin_amdgcn_mfma_f32_16x16x32_bf16(qreg[1][kk], bk, sf[1][n], 0, 0, 0);
      }
    }

    // ---- online softmax (rows: wq + qt*16 + lg*4 + r; cols: t0 + n*16 + lr) ----
    const bool needmask = (t0 + KVBLK - 1 > wq);
#pragma unroll
    for (int qt = 0; qt < 2; qt++) {
#pragma unroll
      for (int r = 0; r < 4; r++) {
        const int qrow = wq + qt * 16 + lg * 4 + r;
        float v0 = sf[qt][0][r], v1 = sf[qt][1][r], v2 = sf[qt][2][r], v3 = sf[qt][3][r];
        if (needmask) {
          if (t0 + 0 * 16 + lr > qrow) v0 = -INFINITY;
          if (t0 + 1 * 16 + lr > qrow) v1 = -INFINITY;
          if (t0 + 2 * 16 + lr > qrow) v2 = -INFINITY;
          if (t0 + 3 * 16 + lr > qrow) v3 = -INFINITY;
        }
        float mx = fmaxf(fmaxf(v0, v1), fmaxf(v2, v3));
        mx = fmaxf(mx, __shfl_xor(mx, 1));
        mx = fmaxf(mx, __shfl_xor(mx, 2));
        mx = fmaxf(mx, __shfl_xor(mx, 4));
        mx = fmaxf(mx, __shfl_xor(mx, 8));
        const float mnew = fmaxf(mrun[qt][r], mx);
        const float corr = __expf(mrun[qt][r] - mnew);
        mrun[qt][r] = mnew;
        float p0 = __expf(v0 - mnew), p1 = __expf(v1 - mnew);
        float p2 = __expf(v2 - mnew), p3 = __expf(v3 - mnew);
        sf[qt][0][r] = p0; sf[qt][1][r] = p1; sf[qt][2][r] = p2; sf[qt][3][r] = p3;
        float sum = (p0 + p1) + (p2 + p3);
        sum += __shfl_xor(sum, 1);
        sum += __shfl_xor(sum, 2);
        sum += __shfl_xor(sum, 4);
        sum += __shfl_xor(sum, 8);
        lrun[qt][r] = lrun[qt][r] * corr + sum;
#pragma unroll
        for (int db = 0; db < 8; db++) acc[qt][db][r] *= corr;
      }
      // ---- P -> per-wave LDS [32][64] swizzled ----
#pragma unroll
      for (int r = 0; r < 4; r++) {
        const int prow = qt * 16 + lg * 4 + r;
        char* pbase = Ps + prow * 128;
        const int pm = (prow & 7) << 4;
#pragma unroll
        for (int n = 0; n < 4; n++)
          *(bf16_t*)(pbase + (((n * 16 + lr) * 2) ^ pm)) = (bf16_t)sf[qt][n][r];
      }
    }

    // ---- O += P @ V ----
#pragma unroll
    for (int kk = 0; kk < 2; kk++) {
      const int colb = ((kk * 32 + lg * 8) * 2) ^ xmask;
      const bf16x8 ap0 = *(const bf16x8*)(Ps + lr * 128 + colb);
      const bf16x8 ap1 = *(const bf16x8*)(Ps + (16 + lr) * 128 + colb);
#pragma unroll
      for (int db = 0; db < 8; db++) {
        const bf16x8 bv = *(const bf16x8*)(Vs + (db * 16 + lr) * 128 + colb);
        acc[0][db] = __builtin_amdgcn_mfma_f32_16x16x32_bf16(ap0, bv, acc[0][db], 0, 0, 0);
        acc[1][db] = __builtin_amdgcn_mfma_f32_16x16x32_bf16(ap1, bv, acc[1][db], 0, 0, 0);
      }
    }
  }

  // ---- epilogue: O = acc / l ----
#pragma unroll
  for (int qt = 0; qt < 2; qt++)
#pragma unroll
    for (int r = 0; r < 4; r++) {
      const int q = wq + qt * 16 + lg * 4 + r;
      const float inv = 1.f / lrun[qt][r];
#pragma unroll
      for (int db = 0; db < 8; db++)
        O[(((size_t)b * S_ + q) * NH_ + h) * HD_ + db * 16 + lr] = (bf16_t)(acc[qt][db][r] * inv);
    }
}

extern "C" void kernel_launch(void* const* d_in, const int* in_sizes, int n_in,
                              void* d_out, int out_size, void* d_ws, size_t ws_size,
                              hipStream_t stream) {
  const float* x    = (const float*)d_in[0];
  const float* fcos = (const float*)d_in[1];
  const float* fsin = (const float*)d_in[2];
  const float* wq   = (const float*)d_in[3];
  const float* wk   = (const float*)d_in[4];
  const float* wv   = (const float*)d_in[5];
  const float* wo   = (const float*)d_in[6];
  float* out = (float*)d_out;

  char* ws = (char*)d_ws;
  bf16_t* x_bf  = (bf16_t*)(ws);                    // 33.5 MB
  bf16_t* wt    = (bf16_t*)(ws + 33554432);         // 33.5 MB (wq^T, later wo^T)
  bf16_t* wkt   = (bf16_t*)(ws + 67108864);         // 8.4 MB
  bf16_t* wvt   = (bf16_t*)(ws + 75497472);         // 8.4 MB
  bf16_t* q_bf  = (bf16_t*)(ws + 83886080);         // 33.5 MB
  bf16_t* k_bf  = (bf16_t*)(ws + 117440512);        // 8.4 MB
  bf16_t* xv_bf = (bf16_t*)(ws + 125829120);        // 8.4 MB
  bf16_t* vt    = (bf16_t*)(ws + 134217728);        // 8.4 MB
  bf16_t* attn  = (bf16_t*)(ws + 142606336);        // 33.5 MB  (end ~176 MB)

  // 1. convert x to bf16
  convert_f32_bf16<<<8192, 256, 0, stream>>>(x, x_bf, (size_t)2097152);
  // 2. transpose+convert weights (to (N,K) bf16)
  transpose_convert<<<dim3(128, 128), 256, 0, stream>>>(wq, wt, 4096, 4096);
  transpose_convert<<<dim3(32, 128), 256, 0, stream>>>(wk, wkt, 4096, 1024);
  transpose_convert<<<dim3(32, 128), 256, 0, stream>>>(wv, wvt, 4096, 1024);
  // 3. QKV projections (bf16 out)
  gemm_nt<bf16_t><<<dim3(32, 32), 256, 0, stream>>>(x_bf, wt, q_bf, 4096, 4096, 4096);
  gemm_nt<bf16_t><<<dim3(8, 32), 256, 0, stream>>>(x_bf, wkt, k_bf, 4096, 1024, 4096);
  gemm_nt<bf16_t><<<dim3(8, 32), 256, 0, stream>>>(x_bf, wvt, xv_bf, 4096, 1024, 4096);
  // 4. RoPE in-place on q,k
  rope_inplace<<<8192, 256, 0, stream>>>(q_bf, fcos, fsin, NH_, (size_t)2097152);
  rope_inplace<<<2048, 256, 0, stream>>>(k_bf, fcos, fsin, NKV_, (size_t)524288);
  // 5. V -> (B,NKV,HD,S)
  transpose_v<<<dim3(64, 4, 16), 256, 0, stream>>>(xv_bf, vt);
  // 6. wo^T into the big weight slot (wq^T no longer needed)
  transpose_convert<<<dim3(128, 128), 256, 0, stream>>>(wo, wt, 4096, 4096);
  // 7. flash attention v2
  flash_attn2<<<dim3(8, 32, 2), 512, 0, stream>>>(q_bf, k_bf, vt, attn);
  // 8. output projection (f32 out)
  gemm_nt<float><<<dim3(32, 32), 256, 0, stream>>>(attn, wt, out, 4096, 4096, 4096);
}

// Round 3
// 816.386 us; speedup vs baseline: 1.2401x; 1.1792x over previous
//
#include <hip/hip_runtime.h>
#include <hip/hip_bf16.h>
#include <math.h>

typedef __bf16 bf16_t;
typedef __bf16 bf16x4 __attribute__((ext_vector_type(4)));
typedef __bf16 bf16x8 __attribute__((ext_vector_type(8)));
typedef float  f32x4  __attribute__((ext_vector_type(4)));

#define B_   2
#define S_   2048
#define D_   4096
#define NH_  32
#define NKV_ 8
#define HD_  128
#define NREP_ 4

static __device__ __forceinline__ void gload_lds16(const bf16_t* g, bf16_t* l) {
  __builtin_amdgcn_global_load_lds(
      (const __attribute__((address_space(1))) void*)g,
      (__attribute__((address_space(3))) void*)l, 16, 0, 0);
}

// ---------------- elementwise f32 -> bf16 convert (vectorized) ----------------
__global__ void convert_f32_bf16(const float* __restrict__ in, bf16_t* __restrict__ out,
                                 size_t n8) {
  size_t i = (size_t)blockIdx.x * blockDim.x + threadIdx.x;
  if (i >= n8) return;
  f32x4 a = *(const f32x4*)(in + i * 8);
  f32x4 b = *(const f32x4*)(in + i * 8 + 4);
  bf16x8 o;
  o[0] = (bf16_t)a[0]; o[1] = (bf16_t)a[1]; o[2] = (bf16_t)a[2]; o[3] = (bf16_t)a[3];
  o[4] = (bf16_t)b[0]; o[5] = (bf16_t)b[1]; o[6] = (bf16_t)b[2]; o[7] = (bf16_t)b[3];
  *(bf16x8*)(out + i * 8) = o;
}

// ---------------- transpose + convert: in (R,C) f32 -> out (C,R) bf16 ----------------
__global__ void transpose_convert(const float* __restrict__ in, bf16_t* __restrict__ out,
                                  int R, int C) {
  __shared__ float tile[32][33];
  const int c0 = blockIdx.x * 32, r0 = blockIdx.y * 32;
  const int tc = threadIdx.x & 31, tr = threadIdx.x >> 5;  // tr in 0..7
#pragma unroll
  for (int i = 0; i < 4; i++) {
    int r = tr + i * 8;
    tile[r][tc] = in[(size_t)(r0 + r) * C + c0 + tc];
  }
  __syncthreads();
#pragma unroll
  for (int i = 0; i < 4; i++) {
    int r = tr + i * 8;  // row of OUT tile = col of in
    out[(size_t)(c0 + r) * R + r0 + tc] = (bf16_t)tile[tc][r];
  }
}

// ---------------- transpose V: (B,S,NKV,HD) bf16 -> (B,NKV,HD,S) bf16 ----------------
__global__ void transpose_v(const bf16_t* __restrict__ in, bf16_t* __restrict__ out) {
  __shared__ bf16_t tile[32][33];
  const int t0 = blockIdx.x * 32, d0 = blockIdx.y * 32;
  const int bg = blockIdx.z, b = bg / NKV_, g = bg % NKV_;
  const bf16_t* ibase = in + ((size_t)b * S_ * NKV_ + g) * HD_;
  bf16_t* obase = out + ((size_t)b * NKV_ + g) * (size_t)HD_ * S_;
  const int tc = threadIdx.x & 31, tr = threadIdx.x >> 5;
#pragma unroll
  for (int i = 0; i < 4; i++) {
    int t = t0 + tr + i * 8;
    tile[tr + i * 8][tc] = ibase[(size_t)t * NKV_ * HD_ + d0 + tc];
  }
  __syncthreads();
#pragma unroll
  for (int i = 0; i < 4; i++) {
    int d = d0 + tr + i * 8;
    obase[(size_t)d * S_ + t0 + tc] = tile[tc][tr + i * 8];
  }
}

// ---------------- RoPE in-place on bf16 (B,S,nh,HD) ----------------
__global__ void rope_inplace(bf16_t* __restrict__ x, const float* __restrict__ cosT,
                             const float* __restrict__ sinT, int nheads, size_t nchunks) {
  size_t i = (size_t)blockIdx.x * blockDim.x + threadIdx.x;
  if (i >= nchunks) return;
  const int d8 = (int)(i & 15);          // 16 chunks of 8 elems per head-row (HD=128)
  const size_t row = i >> 4;             // (b*S + s)*nheads + h
  const int s = (int)((row / nheads) % S_);
  bf16x8 v = *(bf16x8*)(x + i * 8);
  f32x4 c  = *(const f32x4*)(cosT + (size_t)s * 64 + d8 * 4);
  f32x4 sn = *(const f32x4*)(sinT + (size_t)s * 64 + d8 * 4);
  bf16x8 o;
#pragma unroll
  for (int j = 0; j < 4; j++) {
    float re = (float)v[2 * j], im = (float)v[2 * j + 1];
    o[2 * j]     = (bf16_t)(re * c[j] - im * sn[j]);
    o[2 * j + 1] = (bf16_t)(re * sn[j] + im * c[j]);
  }
  *(bf16x8*)(x + i * 8) = o;
}

// ---------------- NT GEMM: C(M,N) = A(M,K) @ Bt(N,K)^T, bf16 in, OutT out ----------------
template <typename OutT>
__global__ __launch_bounds__(256) void gemm_nt(const bf16_t* __restrict__ A,
                                               const bf16_t* __restrict__ Bt,
                                               OutT* __restrict__ C, int M, int N, int K) {
  __shared__ __align__(16) bf16_t As[128][32];
  __shared__ __align__(16) bf16_t Bs[128][32];
  const int t = threadIdx.x, w = t >> 6, l = t & 63;
  const int wm = w >> 1, wn = w & 1;
  const int m0 = blockIdx.y * 128, n0 = blockIdx.x * 128;
  const int lr = l & 15, lg = l >> 4;
  const int srow = l >> 2, scol = (l & 3) * 8;

  f32x4 zero = {0.f, 0.f, 0.f, 0.f};
  f32x4 acc[4][4];
#pragma unroll
  for (int i = 0; i < 4; i++)
#pragma unroll
    for (int j = 0; j < 4; j++) acc[i][j] = zero;

  const size_t arow = (size_t)(m0 + w * 16 + srow) * K + scol;
  const size_t brow = (size_t)(n0 + w * 16 + srow) * K + scol;

  for (int k0 = 0; k0 < K; k0 += 32) {
#pragma unroll
    for (int j = 0; j < 2; j++) {
      gload_lds16(A + arow + (size_t)j * 64 * K + k0, &As[j * 64 + w * 16][0]);
      gload_lds16(Bt + brow + (size_t)j * 64 * K + k0, &Bs[j * 64 + w * 16][0]);
    }
    __syncthreads();
    bf16x8 af[4], bfr[4];
#pragma unroll
    for (int m = 0; m < 4; m++) af[m] = *(const bf16x8*)&As[wm * 64 + m * 16 + lr][lg * 8];
#pragma unroll
    for (int n = 0; n < 4; n++) bfr[n] = *(const bf16x8*)&Bs[wn * 64 + n * 16 + lr][lg * 8];
#pragma unroll
    for (int m = 0; m < 4; m++)
#pragma unroll
      for (int n = 0; n < 4; n++)
        acc[m][n] = __builtin_amdgcn_mfma_f32_16x16x32_bf16(af[m], bfr[n], acc[m][n], 0, 0, 0);
    __syncthreads();
  }
#pragma unroll
  for (int m = 0; m < 4; m++)
#pragma unroll
    for (int n = 0; n < 4; n++) {
      const int row = m0 + wm * 64 + m * 16 + lg * 4;
      const int col = n0 + wn * 64 + n * 16 + lr;
#pragma unroll
      for (int r = 0; r < 4; r++) C[(size_t)(row + r) * N + col] = (OutT)acc[m][n][r];
    }
}

// ---------------- flash attention v3 (causal, GQA, balanced pairs, swapped QK^T) ----------------
// Q:(B,S,NH,HD) K:(B,S,NKV,HD) Vt:(B,NKV,HD,S) O:(B,S,NH,HD), all bf16.
// 4 waves x 32 q-rows = QBLK 128; block handles q-tiles {pair, 15-pair} -> constant work.
// Swapped QK^T: S^T = mfma(K, Q); softmax = in-lane 16-max + 2 shfl; P packed b64 -> LDS.
#define QBLK 128
#define KVBLK 64
__global__ __launch_bounds__(256, 2) void flash_attn3(const bf16_t* __restrict__ Q,
                                                      const bf16_t* __restrict__ Kg,
                                                      const bf16_t* __restrict__ Vt,
                                                      bf16_t* __restrict__ O) {
  const int pair = blockIdx.x;  // 0..7
  const int h = blockIdx.y, b = blockIdx.z;
  const int g = h >> 2;  // NREP=4
  const int t = threadIdx.x, w = t >> 6, l = t & 63;
  const int lr = l & 15, lg = l >> 4;

  __shared__ __align__(16) char lds[49152];
  char* Ks = lds;                     // [64][128] bf16, 256B rows, swizzled
  char* Vs = lds + 16384;             // [128][64] bf16, 128B rows, swizzled (V^T tile)
  char* Ps = lds + 32768 + w * 4096;  // per-wave [32][64] bf16, 128B rows, swizzled

  const float scale = 0.08838834764831845f;
  const int xm = (lr & 7) << 4;

  for (int phase = 0; phase < 2; phase++) {
    const int qtile = phase ? (15 - pair) : pair;
    const int q0 = qtile * QBLK;
    const int wq = q0 + w * 32;  // this wave's first q row

    // Q -> registers (B-operand layout), scale folded in
    bf16x8 qreg[2][4];
#pragma unroll
    for (int qt = 0; qt < 2; qt++)
#pragma unroll
      for (int kk = 0; kk < 4; kk++) {
        bf16x8 v = *(const bf16x8*)&Q[(((size_t)b * S_ + wq + qt * 16 + lr) * NH_ + h) * HD_ +
                                      kk * 32 + lg * 8];
#pragma unroll
        for (int j = 0; j < 8; j++) v[j] = (bf16_t)((float)v[j] * scale);
        qreg[qt][kk] = v;
      }

    float mrun[2] = {-INFINITY, -INFINITY};
    float lrun[2] = {0.f, 0.f};
    f32x4 acc[2][8];
    const f32x4 zero = {0.f, 0.f, 0.f, 0.f};
#pragma unroll
    for (int qt = 0; qt < 2; qt++)
#pragma unroll
      for (int d = 0; d < 8; d++) acc[qt][d] = zero;

    const int nkb = (q0 + QBLK) >> 6;
    for (int kb = 0; kb < nkb; kb++) {
      const int t0 = kb * KVBLK;
      __syncthreads();  // previous tile's readers done
      // ---- stage K [64][128] ----
#pragma unroll
      for (int i = 0; i < 4; i++) {
        const int c = t + i * 256;
        const int row = c >> 4, sl = c & 15;
        bf16x8 kv = *(const bf16x8*)&Kg[(((size_t)b * S_ + t0 + row) * NKV_ + g) * HD_ + sl * 8];
        *(bf16x8*)(Ks + row * 256 + ((sl * 16) ^ ((row & 7) << 4))) = kv;
      }
      // ---- stage V^T [128][64] ----
#pragma unroll
      for (int i = 0; i < 4; i++) {
        const int c = t + i * 256;
        const int row = c >> 3, sl = c & 7;
        bf16x8 vv = *(const bf16x8*)&Vt[(((size_t)b * NKV_ + g) * HD_ + row) * S_ + t0 + sl * 8];
        *(bf16x8*)(Vs + row * 128 + ((sl * 16) ^ ((row & 7) << 4))) = vv;
      }
      __syncthreads();

      if (t0 > wq + 31) continue;  // causal: wave has no work this tile

      // ---- S^T = K @ Q^T : st[n][qt][r] = S[key=t0+n*16+lg*4+r][q=wq+qt*16+lr] ----
      f32x4 st[4][2];
#pragma unroll
      for (int n = 0; n < 4; n++) { st[n][0] = zero; st[n][1] = zero; }
#pragma unroll
      for (int kk = 0; kk < 4; kk++) {
        const int colb = (kk * 64 + lg * 16) ^ xm;
#pragma unroll
        for (int n = 0; n < 4; n++) {
          const bf16x8 ak = *(const bf16x8*)(Ks + (n * 16 + lr) * 256 + colb);
          st[n][0] = __builtin_amdgcn_mfma_f32_16x16x32_bf16(ak, qreg[0][kk], st[n][0], 0, 0, 0);
          st[n][1] = __builtin_amdgcn_mfma_f32_16x16x32_bf16(ak, qreg[1][kk], st[n][1], 0, 0, 0);
        }
      }

      // ---- online softmax: q = wq + qt*16 + lr (per-lane!), keys in-lane ----
      const bool needmask = (t0 + KVBLK - 1 > wq);
#pragma unroll
      for (int qt = 0; qt < 2; qt++) {
        const int q = wq + qt * 16 + lr;
        if (needmask) {
#pragma unroll
          for (int n = 0; n < 4; n++)
#pragma unroll
            for (int r = 0; r < 4; r++)
              if (t0 + n * 16 + lg * 4 + r > q) st[n][qt][r] = -INFINITY;
        }
        float mx = -INFINITY;
#pragma unroll
        for (int n = 0; n < 4; n++)
#pragma unroll
          for (int r = 0; r < 4; r++) mx = fmaxf(mx, st[n][qt][r]);
        mx = fmaxf(mx, __shfl_xor(mx, 16));
        mx = fmaxf(mx, __shfl_xor(mx, 32));
        const float mnew = fmaxf(mrun[qt], mx);
        const float corr = __expf(mrun[qt] - mnew);
        mrun[qt] = mnew;
        float sum = 0.f;
        bf16x4 pk[4];
#pragma unroll
        for (int n = 0; n < 4; n++) {
#pragma unroll
          for (int r = 0; r < 4; r++) {
            const float p = __expf(st[n][qt][r] - mnew);
            sum += p;
            pk[n][r] = (bf16_t)p;
          }
        }
        sum += __shfl_xor(sum, 16);
        sum += __shfl_xor(sum, 32);
        lrun[qt] = lrun[qt] * corr + sum;
        // P^T -> P: lane writes its 4-key packs for its q-column
        {
          char* pbase = Ps + (qt * 16 + lr) * 128;
#pragma unroll
          for (int n = 0; n < 4; n++)
            *(bf16x4*)(pbase + ((n * 32 + lg * 8) ^ xm)) = pk[n];
        }
        // rescale acc: acc rows are q16 = lg*4 + r -> fetch corr from lane lr' = lg*4+r
#pragma unroll
        for (int r = 0; r < 4; r++) {
          const float cb = __shfl(corr, lg * 4 + r);
#pragma unroll
          for (int db = 0; db < 8; db++) acc[qt][db][r] *= cb;
        }
      }

      // ---- O += P @ V  (Ps is per-wave: no barrier needed) ----
#pragma unroll
      for (int kk = 0; kk < 2; kk++) {
        const int colb = (kk * 64 + lg * 16) ^ xm;
        const bf16x8 ap0 = *(const bf16x8*)(Ps + lr * 128 + colb);
        const bf16x8 ap1 = *(const bf16x8*)(Ps + (16 + lr) * 128 + colb);
#pragma unroll
        for (int db = 0; db < 8; db++) {
          const bf16x8 bv = *(const bf16x8*)(Vs + (db * 16 + lr) * 128 + colb);
          acc[0][db] = __builtin_amdgcn_mfma_f32_16x16x32_bf16(ap0, bv, acc[0][db], 0, 0, 0);
          acc[1][db] = __builtin_amdgcn_mfma_f32_16x16x32_bf16(ap1, bv, acc[1][db], 0, 0, 0);
        }
      }
    }

    // ---- epilogue: O = acc / l ----
#pragma unroll
    for (int qt = 0; qt < 2; qt++) {
      const float linv = 1.f / lrun[qt];
#pragma unroll
      for (int r = 0; r < 4; r++) {
        const float li = __shfl(linv, lg * 4 + r);
        const int q = wq + qt * 16 + lg * 4 + r;
#pragma unroll
        for (int db = 0; db < 8; db++)
          O[(((size_t)b * S_ + q) * NH_ + h) * HD_ + db * 16 + lr] = (bf16_t)(acc[qt][db][r] * li);
      }
    }
    __syncthreads();  // protect LDS before next phase restages
  }
}

extern "C" void kernel_launch(void* const* d_in, const int* in_sizes, int n_in,
                              void* d_out, int out_size, void* d_ws, size_t ws_size,
                              hipStream_t stream) {
  const float* x    = (const float*)d_in[0];
  const float* fcos = (const float*)d_in[1];
  const float* fsin = (const float*)d_in[2];
  const float* wq   = (const float*)d_in[3];
  const float* wk   = (const float*)d_in[4];
  const float* wv   = (const float*)d_in[5];
  const float* wo   = (const float*)d_in[6];
  float* out = (float*)d_out;

  char* ws = (char*)d_ws;
  bf16_t* x_bf  = (bf16_t*)(ws);                    // 33.5 MB
  bf16_t* wt    = (bf16_t*)(ws + 33554432);         // 33.5 MB (wq^T, later wo^T)
  bf16_t* wkt   = (bf16_t*)(ws + 67108864);         // 8.4 MB
  bf16_t* wvt   = (bf16_t*)(ws + 75497472);         // 8.4 MB
  bf16_t* q_bf  = (bf16_t*)(ws + 83886080);         // 33.5 MB
  bf16_t* k_bf  = (bf16_t*)(ws + 117440512);        // 8.4 MB
  bf16_t* xv_bf = (bf16_t*)(ws + 125829120);        // 8.4 MB
  bf16_t* vt    = (bf16_t*)(ws + 134217728);        // 8.4 MB
  bf16_t* attn  = (bf16_t*)(ws + 142606336);        // 33.5 MB  (end ~176 MB)

  // 1. convert x to bf16
  convert_f32_bf16<<<8192, 256, 0, stream>>>(x, x_bf, (size_t)2097152);
  // 2. transpose+convert weights (to (N,K) bf16)
  transpose_convert<<<dim3(128, 128), 256, 0, stream>>>(wq, wt, 4096, 4096);
  transpose_convert<<<dim3(32, 128), 256, 0, stream>>>(wk, wkt, 4096, 1024);
  transpose_convert<<<dim3(32, 128), 256, 0, stream>>>(wv, wvt, 4096, 1024);
  // 3. QKV projections (bf16 out)
  gemm_nt<bf16_t><<<dim3(32, 32), 256, 0, stream>>>(x_bf, wt, q_bf, 4096, 4096, 4096);
  gemm_nt<bf16_t><<<dim3(8, 32), 256, 0, stream>>>(x_bf, wkt, k_bf, 4096, 1024, 4096);
  gemm_nt<bf16_t><<<dim3(8, 32), 256, 0, stream>>>(x_bf, wvt, xv_bf, 4096, 1024, 4096);
  // 4. RoPE in-place on q,k
  rope_inplace<<<8192, 256, 0, stream>>>(q_bf, fcos, fsin, NH_, (size_t)2097152);
  rope_inplace<<<2048, 256, 0, stream>>>(k_bf, fcos, fsin, NKV_, (size_t)524288);
  // 5. V -> (B,NKV,HD,S)
  transpose_v<<<dim3(64, 4, 16), 256, 0, stream>>>(xv_bf, vt);
  // 6. wo^T into the big weight slot (wq^T no longer needed)
  transpose_convert<<<dim3(128, 128), 256, 0, stream>>>(wo, wt, 4096, 4096);
  // 7. flash attention v3 (balanced pairs)
  flash_attn3<<<dim3(8, 32, 2), 256, 0, stream>>>(q_bf, k_bf, vt, attn);
  // 8. output projection (f32 out)
  gemm_nt<float><<<dim3(32, 32), 256, 0, stream>>>(attn, wt, out, 4096, 4096, 4096);
}

// Round 4
// 546.845 us; speedup vs baseline: 1.8514x; 1.4929x over previous
//
#include <hip/hip_runtime.h>
#include <hip/hip_bf16.h>
#include <math.h>

typedef __bf16 bf16_t;
typedef __bf16 bf16x4 __attribute__((ext_vector_type(4)));
typedef __bf16 bf16x8 __attribute__((ext_vector_type(8)));
typedef float  f32x4  __attribute__((ext_vector_type(4)));

#define B_   2
#define S_   2048
#define D_   4096
#define NH_  32
#define NKV_ 8
#define HD_  128
#define NREP_ 4
#define QKVN 6144   // fused QKV output width: 4096 q + 1024 k + 1024 v

static __device__ __forceinline__ void gload_lds16(const bf16_t* g, bf16_t* l) {
  __builtin_amdgcn_global_load_lds(
      (const __attribute__((address_space(1))) void*)g,
      (__attribute__((address_space(3))) void*)l, 16, 0, 0);
}

// ---------------- elementwise f32 -> bf16 convert (vectorized) ----------------
__global__ void convert_f32_bf16(const float* __restrict__ in, bf16_t* __restrict__ out,
                                 size_t n8) {
  size_t i = (size_t)blockIdx.x * blockDim.x + threadIdx.x;
  if (i >= n8) return;
  f32x4 a = *(const f32x4*)(in + i * 8);
  f32x4 b = *(const f32x4*)(in + i * 8 + 4);
  bf16x8 o;
  o[0] = (bf16_t)a[0]; o[1] = (bf16_t)a[1]; o[2] = (bf16_t)a[2]; o[3] = (bf16_t)a[3];
  o[4] = (bf16_t)b[0]; o[5] = (bf16_t)b[1]; o[6] = (bf16_t)b[2]; o[7] = (bf16_t)b[3];
  *(bf16x8*)(out + i * 8) = o;
}

// ---------------- transpose + convert: in (R,C) f32 -> out (C,R) bf16 ----------------
__global__ void transpose_convert(const float* __restrict__ in, bf16_t* __restrict__ out,
                                  int R, int C) {
  __shared__ float tile[32][33];
  const int c0 = blockIdx.x * 32, r0 = blockIdx.y * 32;
  const int tc = threadIdx.x & 31, tr = threadIdx.x >> 5;  // tr in 0..7
#pragma unroll
  for (int i = 0; i < 4; i++) {
    int r = tr + i * 8;
    tile[r][tc] = in[(size_t)(r0 + r) * C + c0 + tc];
  }
  __syncthreads();
#pragma unroll
  for (int i = 0; i < 4; i++) {
    int r = tr + i * 8;  // row of OUT tile = col of in
    out[(size_t)(c0 + r) * R + r0 + tc] = (bf16_t)tile[tc][r];
  }
}

// ---------------- transpose V: qkv cols [5120,6144) -> (B,NKV,HD,S) bf16 ----------------
__global__ void transpose_v(const bf16_t* __restrict__ qkv, bf16_t* __restrict__ out) {
  __shared__ bf16_t tile[32][33];
  const int t0 = blockIdx.x * 32, d0 = blockIdx.y * 32;
  const int bg = blockIdx.z, b = bg / NKV_, g = bg % NKV_;
  const bf16_t* ibase = qkv + (size_t)b * S_ * QKVN + 5120 + g * HD_;
  bf16_t* obase = out + ((size_t)b * NKV_ + g) * (size_t)HD_ * S_;
  const int tc = threadIdx.x & 31, tr = threadIdx.x >> 5;
#pragma unroll
  for (int i = 0; i < 4; i++) {
    int t = t0 + tr + i * 8;
    tile[tr + i * 8][tc] = ibase[(size_t)t * QKVN + d0 + tc];
  }
  __syncthreads();
#pragma unroll
  for (int i = 0; i < 4; i++) {
    int d = d0 + tr + i * 8;
    obase[(size_t)d * S_ + t0 + tc] = tile[tc][tr + i * 8];
  }
}

// ---------------- RoPE in-place on qkv buffer (row stride QKVN) ----------------
// chunk i: d8 = i&15, h = (i>>4)&(2^lgh-1), pos = i>>(4+lgh), s = pos & (S_-1)
__global__ void rope_inplace(bf16_t* __restrict__ x, const float* __restrict__ cosT,
                             const float* __restrict__ sinT, int lgh, size_t nchunks) {
  size_t i = (size_t)blockIdx.x * blockDim.x + threadIdx.x;
  if (i >= nchunks) return;
  const int d8 = (int)(i & 15);
  const int h = (int)((i >> 4) & ((1u << lgh) - 1));
  const size_t pos = i >> (4 + lgh);
  const int s = (int)(pos & (S_ - 1));
  bf16_t* p = x + pos * QKVN + h * HD_ + d8 * 8;
  bf16x8 v = *(bf16x8*)p;
  f32x4 c  = *(const f32x4*)(cosT + (size_t)s * 64 + d8 * 4);
  f32x4 sn = *(const f32x4*)(sinT + (size_t)s * 64 + d8 * 4);
  bf16x8 o;
#pragma unroll
  for (int j = 0; j < 4; j++) {
    float re = (float)v[2 * j], im = (float)v[2 * j + 1];
    o[2 * j]     = (bf16_t)(re * c[j] - im * sn[j]);
    o[2 * j + 1] = (bf16_t)(re * sn[j] + im * c[j]);
  }
  *(bf16x8*)p = o;
}

// ---------------- 256x256 NT GEMM, BK=32, depth-3 counted-vmcnt pipeline ----------------
// C(M,N) = A(M,K) @ Bt(N,K)^T. 512 threads = 8 waves (2M x 4N), wave tile 128x64.
// LDS: 4 K-tile buffers x (A[256][32] + B[256][32]) bf16 = 128 KiB (dynamic).
// LDS element (row,c) stored at row*32 + (c ^ ((row&3)<<3)); staged via pre-swizzled
// global source + linear gload_lds dest (guide rule #21).
template <typename OutT>
__global__ __launch_bounds__(512, 2) void gemm_nt256(const bf16_t* __restrict__ A,
                                                     const bf16_t* __restrict__ Bt,
                                                     OutT* __restrict__ C,
                                                     int M, int N, int K) {
  extern __shared__ __align__(16) bf16_t lds[];  // 4 * 16384 elements
  const int t = threadIdx.x;
  const int w = t >> 6, l = t & 63;
  const int wm = w >> 2, wn = w & 3;
  const int lr = l & 15, lg = l >> 4;

  // XCD-chunked swizzle of flattened block id (grid % 8 == 0 for all our launches)
  const int nbx = gridDim.x;
  const int nwg = nbx * gridDim.y;
  const int bid = blockIdx.y * nbx + blockIdx.x;
  const int cpx = nwg >> 3;
  const int sid = (bid & 7) * cpx + (bid >> 3);
  const int n0 = (sid % nbx) * 256;
  const int m0 = (sid / nbx) * 256;

  // staging: thread t handles rows {srow, 128+srow}, 16B slot (t&3), swizzled src col
  const int srow = t >> 2;
  const int colsw = ((t & 3) * 8) ^ (((t >> 2) & 3) << 3);  // elements, < 32
  const bf16_t* Asrc0 = A  + (size_t)(m0 + srow) * K + colsw;
  const bf16_t* Asrc1 = A  + (size_t)(m0 + 128 + srow) * K + colsw;
  const bf16_t* Bsrc0 = Bt + (size_t)(n0 + srow) * K + colsw;
  const bf16_t* Bsrc1 = Bt + (size_t)(n0 + 128 + srow) * K + colsw;

  f32x4 acc[8][4];
  const f32x4 zero = {0.f, 0.f, 0.f, 0.f};
#pragma unroll
  for (int m = 0; m < 8; m++)
#pragma unroll
    for (int n = 0; n < 4; n++) acc[m][n] = zero;

  // fragment read offset within a row (elements): (lg*8) ^ ((row&3)<<3), row&3 == lr&3
  const int fo = (lg * 8) ^ ((lr & 3) << 3);

  auto STAGE = [&](int buf, int k0) {
    bf16_t* dA = lds + buf * 16384;
    bf16_t* dB = dA + 8192;
    gload_lds16(Asrc0 + k0, dA + t * 8);
    gload_lds16(Asrc1 + k0, dA + 4096 + t * 8);
    gload_lds16(Bsrc0 + k0, dB + t * 8);
    gload_lds16(Bsrc1 + k0, dB + 4096 + t * 8);
  };

  auto COMPUTE = [&](int buf) {
    const bf16_t* pA = lds + buf * 16384;
    const bf16_t* pB = pA + 8192;
    bf16x8 af[8], bfr[4];
#pragma unroll
    for (int m = 0; m < 8; m++)
      af[m] = *(const bf16x8*)(pA + (wm * 128 + m * 16 + lr) * 32 + fo);
#pragma unroll
    for (int n = 0; n < 4; n++)
      bfr[n] = *(const bf16x8*)(pB + (wn * 64 + n * 16 + lr) * 32 + fo);
    __builtin_amdgcn_s_setprio(1);
#pragma unroll
    for (int m = 0; m < 8; m++)
#pragma unroll
      for (int n = 0; n < 4; n++)
        acc[m][n] = __builtin_amdgcn_mfma_f32_16x16x32_bf16(af[m], bfr[n], acc[m][n], 0, 0, 0);
    __builtin_amdgcn_s_setprio(0);
  };

  const int KT = K >> 5;  // K-tiles of 32 (KT >= 4, multiple cases here: 128)

  // prologue: stage T0,T1,T2; wait T0 (8 ops in flight = T1,T2)
  STAGE(0, 0);
  STAGE(1, 32);
  STAGE(2, 64);
  asm volatile("s_waitcnt vmcnt(8)" ::: "memory");
  __builtin_amdgcn_s_barrier();
  __builtin_amdgcn_sched_barrier(0);

  int kt = 0;
  for (; kt < KT - 3; ++kt) {
    STAGE((kt + 3) & 3, (kt + 3) << 5);
    COMPUTE(kt & 3);
    asm volatile("s_waitcnt vmcnt(8)" ::: "memory");  // T_{kt+1} complete, 2 tiles in flight
    __builtin_amdgcn_s_barrier();
    __builtin_amdgcn_sched_barrier(0);
  }
  // tail: kt = KT-3, KT-2, KT-1 (nothing left to stage)
  COMPUTE(kt & 3);
  asm volatile("s_waitcnt vmcnt(4)" ::: "memory");
  __builtin_amdgcn_s_barrier();
  __builtin_amdgcn_sched_barrier(0);
  ++kt;
  COMPUTE(kt & 3);
  asm volatile("s_waitcnt vmcnt(0)" ::: "memory");
  __builtin_amdgcn_s_barrier();
  __builtin_amdgcn_sched_barrier(0);
  ++kt;
  COMPUTE(kt & 3);

  // epilogue
#pragma unroll
  for (int m = 0; m < 8; m++)
#pragma unroll
    for (int n = 0; n < 4; n++) {
      const int row = m0 + wm * 128 + m * 16 + lg * 4;
      const int col = n0 + wn * 64 + n * 16 + lr;
#pragma unroll
      for (int r = 0; r < 4; r++) C[(size_t)(row + r) * N + col] = (OutT)acc[m][n][r];
    }
}

// ---------------- flash attention v3 (causal, GQA, balanced pairs, swapped QK^T) ----------------
// Q,K read from fused qkv (row stride QKVN); Vt:(B,NKV,HD,S); O:(B,S,NH,HD) bf16.
#define QBLK 128
#define KVBLK 64
__global__ __launch_bounds__(256, 2) void flash_attn3(const bf16_t* __restrict__ QKV,
                                                      const bf16_t* __restrict__ Vt,
                                                      bf16_t* __restrict__ O) {
  const int pair = blockIdx.x;  // 0..7
  const int h = blockIdx.y, b = blockIdx.z;
  const int g = h >> 2;  // NREP=4
  const int t = threadIdx.x, w = t >> 6, l = t & 63;
  const int lr = l & 15, lg = l >> 4;

  __shared__ __align__(16) char lds[49152];
  char* Ks = lds;                     // [64][128] bf16, 256B rows, swizzled
  char* Vs = lds + 16384;             // [128][64] bf16, 128B rows, swizzled (V^T tile)
  char* Ps = lds + 32768 + w * 4096;  // per-wave [32][64] bf16, 128B rows, swizzled

  const float scale = 0.08838834764831845f;
  const int xm = (lr & 7) << 4;

  for (int phase = 0; phase < 2; phase++) {
    const int qtile = phase ? (15 - pair) : pair;
    const int q0 = qtile * QBLK;
    const int wq = q0 + w * 32;  // this wave's first q row

    // Q -> registers (B-operand layout), scale folded in
    bf16x8 qreg[2][4];
#pragma unroll
    for (int qt = 0; qt < 2; qt++)
#pragma unroll
      for (int kk = 0; kk < 4; kk++) {
        bf16x8 v = *(const bf16x8*)&QKV[((size_t)b * S_ + wq + qt * 16 + lr) * QKVN +
                                        h * HD_ + kk * 32 + lg * 8];
#pragma unroll
        for (int j = 0; j < 8; j++) v[j] = (bf16_t)((float)v[j] * scale);
        qreg[qt][kk] = v;
      }

    float mrun[2] = {-INFINITY, -INFINITY};
    float lrun[2] = {0.f, 0.f};
    f32x4 acc[2][8];
    const f32x4 zero = {0.f, 0.f, 0.f, 0.f};
#pragma unroll
    for (int qt = 0; qt < 2; qt++)
#pragma unroll
      for (int d = 0; d < 8; d++) acc[qt][d] = zero;

    const int nkb = (q0 + QBLK) >> 6;
    for (int kb = 0; kb < nkb; kb++) {
      const int t0 = kb * KVBLK;
      __syncthreads();  // previous tile's readers done
      // ---- stage K [64][128] ----
#pragma unroll
      for (int i = 0; i < 4; i++) {
        const int c = t + i * 256;
        const int row = c >> 4, sl = c & 15;
        bf16x8 kv = *(const bf16x8*)&QKV[((size_t)b * S_ + t0 + row) * QKVN + 4096 +
                                         g * HD_ + sl * 8];
        *(bf16x8*)(Ks + row * 256 + ((sl * 16) ^ ((row & 7) << 4))) = kv;
      }
      // ---- stage V^T [128][64] ----
#pragma unroll
      for (int i = 0; i < 4; i++) {
        const int c = t + i * 256;
        const int row = c >> 3, sl = c & 7;
        bf16x8 vv = *(const bf16x8*)&Vt[(((size_t)b * NKV_ + g) * HD_ + row) * S_ + t0 + sl * 8];
        *(bf16x8*)(Vs + row * 128 + ((sl * 16) ^ ((row & 7) << 4))) = vv;
      }
      __syncthreads();

      if (t0 > wq + 31) continue;  // causal: wave has no work this tile

      // ---- S^T = K @ Q^T : st[n][qt][r] = S[key=t0+n*16+lg*4+r][q=wq+qt*16+lr] ----
      f32x4 st[4][2];
#pragma unroll
      for (int n = 0; n < 4; n++) { st[n][0] = zero; st[n][1] = zero; }
#pragma unroll
      for (int kk = 0; kk < 4; kk++) {
        const int colb = (kk * 64 + lg * 16) ^ xm;
#pragma unroll
        for (int n = 0; n < 4; n++) {
          const bf16x8 ak = *(const bf16x8*)(Ks + (n * 16 + lr) * 256 + colb);
          st[n][0] = __builtin_amdgcn_mfma_f32_16x16x32_bf16(ak, qreg[0][kk], st[n][0], 0, 0, 0);
          st[n][1] = __builtin_amdgcn_mfma_f32_16x16x32_bf16(ak, qreg[1][kk], st[n][1], 0, 0, 0);
        }
      }

      // ---- online softmax: q = wq + qt*16 + lr (per-lane!), keys in-lane ----
      const bool needmask = (t0 + KVBLK - 1 > wq);
#pragma unroll
      for (int qt = 0; qt < 2; qt++) {
        const int q = wq + qt * 16 + lr;
        if (needmask) {
#pragma unroll
          for (int n = 0; n < 4; n++)
#pragma unroll
            for (int r = 0; r < 4; r++)
              if (t0 + n * 16 + lg * 4 + r > q) st[n][qt][r] = -INFINITY;
        }
        float mx = -INFINITY;
#pragma unroll
        for (int n = 0; n < 4; n++)
#pragma unroll
          for (int r = 0; r < 4; r++) mx = fmaxf(mx, st[n][qt][r]);
        mx = fmaxf(mx, __shfl_xor(mx, 16));
        mx = fmaxf(mx, __shfl_xor(mx, 32));
        const float mnew = fmaxf(mrun[qt], mx);
        const float corr = __expf(mrun[qt] - mnew);
        mrun[qt] = mnew;
        float sum = 0.f;
        bf16x4 pk[4];
#pragma unroll
        for (int n = 0; n < 4; n++) {
#pragma unroll
          for (int r = 0; r < 4; r++) {
            const float p = __expf(st[n][qt][r] - mnew);
            sum += p;
            pk[n][r] = (bf16_t)p;
          }
        }
        sum += __shfl_xor(sum, 16);
        sum += __shfl_xor(sum, 32);
        lrun[qt] = lrun[qt] * corr + sum;
        // P^T -> P: lane writes its 4-key packs for its q-column
        {
          char* pbase = Ps + (qt * 16 + lr) * 128;
#pragma unroll
          for (int n = 0; n < 4; n++)
            *(bf16x4*)(pbase + ((n * 32 + lg * 8) ^ xm)) = pk[n];
        }
        // rescale acc: acc rows are q16 = lg*4 + r -> fetch corr from lane lr' = lg*4+r
#pragma unroll
        for (int r = 0; r < 4; r++) {
          const float cb = __shfl(corr, lg * 4 + r);
#pragma unroll
          for (int db = 0; db < 8; db++) acc[qt][db][r] *= cb;
        }
      }

      // ---- O += P @ V  (Ps is per-wave: no barrier needed) ----
#pragma unroll
      for (int kk = 0; kk < 2; kk++) {
        const int colb = (kk * 64 + lg * 16) ^ xm;
        const bf16x8 ap0 = *(const bf16x8*)(Ps + lr * 128 + colb);
        const bf16x8 ap1 = *(const bf16x8*)(Ps + (16 + lr) * 128 + colb);
#pragma unroll
        for (int db = 0; db < 8; db++) {
          const bf16x8 bv = *(const bf16x8*)(Vs + (db * 16 + lr) * 128 + colb);
          acc[0][db] = __builtin_amdgcn_mfma_f32_16x16x32_bf16(ap0, bv, acc[0][db], 0, 0, 0);
          acc[1][db] = __builtin_amdgcn_mfma_f32_16x16x32_bf16(ap1, bv, acc[1][db], 0, 0, 0);
        }
      }
    }

    // ---- epilogue: O = acc / l ----
#pragma unroll
    for (int qt = 0; qt < 2; qt++) {
      const float linv = 1.f / lrun[qt];
#pragma unroll
      for (int r = 0; r < 4; r++) {
        const float li = __shfl(linv, lg * 4 + r);
        const int q = wq + qt * 16 + lg * 4 + r;
#pragma unroll
        for (int db = 0; db < 8; db++)
          O[(((size_t)b * S_ + q) * NH_ + h) * HD_ + db * 16 + lr] = (bf16_t)(acc[qt][db][r] * li);
      }
    }
    __syncthreads();  // protect LDS before next phase restages
  }
}

extern "C" void kernel_launch(void* const* d_in, const int* in_sizes, int n_in,
                              void* d_out, int out_size, void* d_ws, size_t ws_size,
                              hipStream_t stream) {
  const float* x    = (const float*)d_in[0];
  const float* fcos = (const float*)d_in[1];
  const float* fsin = (const float*)d_in[2];
  const float* wq   = (const float*)d_in[3];
  const float* wk   = (const float*)d_in[4];
  const float* wv   = (const float*)d_in[5];
  const float* wo   = (const float*)d_in[6];
  float* out = (float*)d_out;

  char* ws = (char*)d_ws;
  bf16_t* x_bf   = (bf16_t*)(ws);               // 33.5 MB  (4096x4096 bf16)
  bf16_t* wqkvT  = (bf16_t*)(ws + 33554432);    // 50.3 MB  (6144x4096 bf16; later wo^T)
  bf16_t* qkv    = (bf16_t*)(ws + 83886080);    // 50.3 MB  (4096x6144 bf16)
  bf16_t* vt     = (bf16_t*)(ws + 134217728);   // 8.4 MB   (B,NKV,HD,S)
  bf16_t* attn   = (bf16_t*)(ws + 142606336);   // 33.5 MB  (4096x4096 bf16) end ~176 MB

  // allow 128 KiB dynamic LDS on the GEMM kernels (idempotent)
  hipFuncSetAttribute(reinterpret_cast<const void*>(gemm_nt256<bf16_t>),
                      hipFuncAttributeMaxDynamicSharedMemorySize, 131072);
  hipFuncSetAttribute(reinterpret_cast<const void*>(gemm_nt256<float>),
                      hipFuncAttributeMaxDynamicSharedMemorySize, 131072);

  // 1. convert x to bf16
  convert_f32_bf16<<<8192, 256, 0, stream>>>(x, x_bf, (size_t)2097152);
  // 2. transpose+convert weights into fused (6144,4096) bf16 W^T
  transpose_convert<<<dim3(128, 128), 256, 0, stream>>>(wq, wqkvT, 4096, 4096);
  transpose_convert<<<dim3(32, 128), 256, 0, stream>>>(wk, wqkvT + (size_t)4096 * 4096, 4096, 1024);
  transpose_convert<<<dim3(32, 128), 256, 0, stream>>>(wv, wqkvT + (size_t)5120 * 4096, 4096, 1024);
  // 3. fused QKV projection: (4096,6144) bf16
  gemm_nt256<bf16_t><<<dim3(24, 16), 512, 131072, stream>>>(x_bf, wqkvT, qkv, 4096, QKVN, 4096);
  // 4. RoPE in-place on q (cols 0..4095) and k (cols 4096..5119)
  rope_inplace<<<8192, 256, 0, stream>>>(qkv, fcos, fsin, 5, (size_t)2097152);
  rope_inplace<<<2048, 256, 0, stream>>>(qkv + 4096, fcos, fsin, 3, (size_t)524288);
  // 5. V -> (B,NKV,HD,S)
  transpose_v<<<dim3(64, 4, 16), 256, 0, stream>>>(qkv, vt);
  // 6. wo^T into the wqkvT slab (QKV GEMM done reading it)
  transpose_convert<<<dim3(128, 128), 256, 0, stream>>>(wo, wqkvT, 4096, 4096);
  // 7. flash attention v3 (balanced pairs)
  flash_attn3<<<dim3(8, 32, 2), 256, 0, stream>>>(qkv, vt, attn);
  // 8. output projection (f32 out)
  gemm_nt256<float><<<dim3(16, 16), 512, 131072, stream>>>(attn, wqkvT, out, 4096, 4096, 4096);
}

// Round 5
// 530.932 us; speedup vs baseline: 1.9069x; 1.0300x over previous
//
#include <hip/hip_runtime.h>
#include <hip/hip_bf16.h>
#include <math.h>

typedef __bf16 bf16_t;
typedef __bf16 bf16x4 __attribute__((ext_vector_type(4)));
typedef __bf16 bf16x8 __attribute__((ext_vector_type(8)));
typedef float  f32x4  __attribute__((ext_vector_type(4)));

#define B_   2
#define S_   2048
#define D_   4096
#define NH_  32
#define NKV_ 8
#define HD_  128
#define NREP_ 4
#define QKVN 6144   // fused QKV output width: 4096 q + 1024 k + 1024 v

static __device__ __forceinline__ void gload_lds16(const bf16_t* g, bf16_t* l) {
  __builtin_amdgcn_global_load_lds(
      (const __attribute__((address_space(1))) void*)g,
      (__attribute__((address_space(3))) void*)l, 16, 0, 0);
}

// ---------------- elementwise f32 -> bf16 convert (vectorized) ----------------
__global__ void convert_f32_bf16(const float* __restrict__ in, bf16_t* __restrict__ out,
                                 size_t n8) {
  size_t i = (size_t)blockIdx.x * blockDim.x + threadIdx.x;
  if (i >= n8) return;
  f32x4 a = *(const f32x4*)(in + i * 8);
  f32x4 b = *(const f32x4*)(in + i * 8 + 4);
  bf16x8 o;
  o[0] = (bf16_t)a[0]; o[1] = (bf16_t)a[1]; o[2] = (bf16_t)a[2]; o[3] = (bf16_t)a[3];
  o[4] = (bf16_t)b[0]; o[5] = (bf16_t)b[1]; o[6] = (bf16_t)b[2]; o[7] = (bf16_t)b[3];
  *(bf16x8*)(out + i * 8) = o;
}

// ---------------- transpose + convert: in (R,C) f32 -> out (C,R) bf16 ----------------
__global__ void transpose_convert(const float* __restrict__ in, bf16_t* __restrict__ out,
                                  int R, int C) {
  __shared__ float tile[32][33];
  const int c0 = blockIdx.x * 32, r0 = blockIdx.y * 32;
  const int tc = threadIdx.x & 31, tr = threadIdx.x >> 5;  // tr in 0..7
#pragma unroll
  for (int i = 0; i < 4; i++) {
    int r = tr + i * 8;
    tile[r][tc] = in[(size_t)(r0 + r) * C + c0 + tc];
  }
  __syncthreads();
#pragma unroll
  for (int i = 0; i < 4; i++) {
    int r = tr + i * 8;  // row of OUT tile = col of in
    out[(size_t)(c0 + r) * R + r0 + tc] = (bf16_t)tile[tc][r];
  }
}

// ---------------- transpose V: qkv cols [5120,6144) -> (B,NKV,HD,S) bf16 ----------------
__global__ void transpose_v(const bf16_t* __restrict__ qkv, bf16_t* __restrict__ out) {
  __shared__ bf16_t tile[32][33];
  const int t0 = blockIdx.x * 32, d0 = blockIdx.y * 32;
  const int bg = blockIdx.z, b = bg / NKV_, g = bg % NKV_;
  const bf16_t* ibase = qkv + (size_t)b * S_ * QKVN + 5120 + g * HD_;
  bf16_t* obase = out + ((size_t)b * NKV_ + g) * (size_t)HD_ * S_;
  const int tc = threadIdx.x & 31, tr = threadIdx.x >> 5;
#pragma unroll
  for (int i = 0; i < 4; i++) {
    int t = t0 + tr + i * 8;
    tile[tr + i * 8][tc] = ibase[(size_t)t * QKVN + d0 + tc];
  }
  __syncthreads();
#pragma unroll
  for (int i = 0; i < 4; i++) {
    int d = d0 + tr + i * 8;
    obase[(size_t)d * S_ + t0 + tc] = tile[tc][tr + i * 8];
  }
}

// ---------------- RoPE in-place on qkv buffer (row stride QKVN) ----------------
__global__ void rope_inplace(bf16_t* __restrict__ x, const float* __restrict__ cosT,
                             const float* __restrict__ sinT, int lgh, size_t nchunks) {
  size_t i = (size_t)blockIdx.x * blockDim.x + threadIdx.x;
  if (i >= nchunks) return;
  const int d8 = (int)(i & 15);
  const int h = (int)((i >> 4) & ((1u << lgh) - 1));
  const size_t pos = i >> (4 + lgh);
  const int s = (int)(pos & (S_ - 1));
  bf16_t* p = x + pos * QKVN + h * HD_ + d8 * 8;
  bf16x8 v = *(bf16x8*)p;
  f32x4 c  = *(const f32x4*)(cosT + (size_t)s * 64 + d8 * 4);
  f32x4 sn = *(const f32x4*)(sinT + (size_t)s * 64 + d8 * 4);
  bf16x8 o;
#pragma unroll
  for (int j = 0; j < 4; j++) {
    float re = (float)v[2 * j], im = (float)v[2 * j + 1];
    o[2 * j]     = (bf16_t)(re * c[j] - im * sn[j]);
    o[2 * j + 1] = (bf16_t)(re * sn[j] + im * c[j]);
  }
  *(bf16x8*)p = o;
}

// ---------------- 256x256 NT GEMM, BK=64, 8-phase counted-vmcnt schedule (m201 port) ----
// C(M,N) = A(M,K) @ Bt(N,K)^T. 512 threads = 8 waves (2M x 4N), wave tile 128x64.
// LDS: 2 K-tile dbufs x (A[256][64] + B[256][64]) bf16 = 128 KiB dynamic.
// Rows are 128B; swizzle: el_in_row ^= (row&7)*8 (both-sides: pre-swizzled global src).
// Stage stream (quarters, 1 gload issue = 8KB each):
//   phase (c,0): kt c+1 A.q1, A.q3   -> dbuf (c+1)&1  [rows freed at (c-1,3) barrier]
//   phase (c,1): kt c+2 B.q0, B.q1   -> dbuf c&1      [B freed at (c,0) barrier]
//   phase (c,2): kt c+2 B.q2, B.q3   -> dbuf c&1
//   phase (c,3): kt c+2 A.q0, A.q2   -> dbuf c&1      [rows freed at (c,1) barrier]
// vmcnt(6) at each (c,3) end retires all issues through (c,0) => kt c+1 complete.
template <typename OutT>
__global__ __launch_bounds__(512, 2) void gemm8p(const bf16_t* __restrict__ Ag,
                                                 const bf16_t* __restrict__ Bg,
                                                 OutT* __restrict__ C,
                                                 int M, int N, int K) {
  extern __shared__ __align__(16) bf16_t lds[];  // 2 * 32768 elements
  const int t = threadIdx.x;
  const int w = t >> 6, l = t & 63;
  const int wm = w >> 2, wn = w & 3;
  const int lr = l & 15, lg = l >> 4;

  // XCD-chunked swizzle of flattened block id (grid % 8 == 0 for all our launches)
  const int nbx = gridDim.x;
  const int nwg = nbx * gridDim.y;
  const int bid = blockIdx.y * nbx + blockIdx.x;
  const int cpx = nwg >> 3;
  const int sid = (bid & 7) * cpx + (bid >> 3);
  const int n0 = (sid % nbx) * 256;
  const int m0 = (sid / nbx) * 256;

  const int srow = t >> 3;                            // 0..63 (row within quarter)
  const int colsw = ((t & 7) ^ (srow & 7)) * 8;       // pre-swizzled source col (elements)
  const int xsw = (lr & 7) * 8;                       // read-side swizzle (elements)

  auto stageA = [&](int db, int k0, int q) {
    gload_lds16(Ag + (size_t)(m0 + q * 64 + srow) * K + k0 + colsw,
                lds + db * 32768 + q * 4096 + t * 8);
  };
  auto stageB = [&](int db, int k0, int q) {
    gload_lds16(Bg + (size_t)(n0 + q * 64 + srow) * K + k0 + colsw,
                lds + db * 32768 + 16384 + q * 4096 + t * 8);
  };

  f32x4 acc[8][4];
  const f32x4 zero = {0.f, 0.f, 0.f, 0.f};
#pragma unroll
  for (int m = 0; m < 8; m++)
#pragma unroll
    for (int n = 0; n < 4; n++) acc[m][n] = zero;

  const int KT = K >> 6;  // K-tiles of 64 (here: 64)

  // ---- prologue: kt0 full (8 issues), kt1 partial (6 issues) ----
#pragma unroll
  for (int q = 0; q < 4; q++) stageA(0, 0, q);
#pragma unroll
  for (int q = 0; q < 4; q++) stageB(0, 0, q);
#pragma unroll
  for (int q = 0; q < 4; q++) stageB(1, 64, q);
  stageA(1, 64, 0);
  stageA(1, 64, 2);
  asm volatile("s_waitcnt vmcnt(6)" ::: "memory");  // kt0 arrived; kt1's 6 in flight
  __builtin_amdgcn_s_barrier();

  for (int c = 0; c < KT; ++c) {
    const int d = c & 1;
    const bf16_t* pA = lds + d * 32768;
    const bf16_t* pB = pA + 16384;
    const bool st2 = (c + 2) < KT;
    const int k2 = (c + 2) << 6;
    bf16x8 bfrag[4][2];

#pragma unroll
    for (int p = 0; p < 4; ++p) {
      // ---- ds_read register subtile ----
      if (p == 0) {
#pragma unroll
        for (int n = 0; n < 4; n++)
#pragma unroll
          for (int ks = 0; ks < 2; ks++)
            bfrag[n][ks] =
                *(const bf16x8*)(pB + (wn * 64 + n * 16 + lr) * 64 + ((ks * 32 + lg * 8) ^ xsw));
      }
      bf16x8 a0 = *(const bf16x8*)(pA + (wm * 128 + (2 * p) * 16 + lr) * 64 + ((lg * 8) ^ xsw));
      bf16x8 a1 = *(const bf16x8*)(pA + (wm * 128 + (2 * p) * 16 + lr) * 64 + ((32 + lg * 8) ^ xsw));
      bf16x8 a2 = *(const bf16x8*)(pA + (wm * 128 + (2 * p + 1) * 16 + lr) * 64 + ((lg * 8) ^ xsw));
      bf16x8 a3 = *(const bf16x8*)(pA + (wm * 128 + (2 * p + 1) * 16 + lr) * 64 + ((32 + lg * 8) ^ xsw));

      // ---- stage prefetch (2 quarter-issues) ----
      if (p == 0) {
        if (c + 1 < KT) { stageA(1 - d, (c + 1) << 6, 1); stageA(1 - d, (c + 1) << 6, 3); }
      } else if (p == 1) {
        if (st2) { stageB(d, k2, 0); stageB(d, k2, 1); }
      } else if (p == 2) {
        if (st2) { stageB(d, k2, 2); stageB(d, k2, 3); }
      } else {
        if (st2) { stageA(d, k2, 0); stageA(d, k2, 2); }
      }

      if (p == 0) asm volatile("s_waitcnt lgkmcnt(8)" ::: "memory");
      __builtin_amdgcn_s_barrier();
      asm volatile("s_waitcnt lgkmcnt(0)" ::: "memory");
      __builtin_amdgcn_sched_barrier(0);

      __builtin_amdgcn_s_setprio(1);
#pragma unroll
      for (int n = 0; n < 4; n++) {
        acc[2 * p][n]     = __builtin_amdgcn_mfma_f32_16x16x32_bf16(a0, bfrag[n][0], acc[2 * p][n], 0, 0, 0);
        acc[2 * p][n]     = __builtin_amdgcn_mfma_f32_16x16x32_bf16(a1, bfrag[n][1], acc[2 * p][n], 0, 0, 0);
        acc[2 * p + 1][n] = __builtin_amdgcn_mfma_f32_16x16x32_bf16(a2, bfrag[n][0], acc[2 * p + 1][n], 0, 0, 0);
        acc[2 * p + 1][n] = __builtin_amdgcn_mfma_f32_16x16x32_bf16(a3, bfrag[n][1], acc[2 * p + 1][n], 0, 0, 0);
      }
      __builtin_amdgcn_s_setprio(0);

      if (p == 3) {
        if (st2) asm volatile("s_waitcnt vmcnt(6)" ::: "memory");
        else     asm volatile("s_waitcnt vmcnt(0)" ::: "memory");
      }
      __builtin_amdgcn_s_barrier();
    }
  }

  // ---- epilogue ----
#pragma unroll
  for (int m = 0; m < 8; m++)
#pragma unroll
    for (int n = 0; n < 4; n++) {
      const int row = m0 + wm * 128 + m * 16 + lg * 4;
      const int col = n0 + wn * 64 + n * 16 + lr;
#pragma unroll
      for (int r = 0; r < 4; r++) C[(size_t)(row + r) * N + col] = (OutT)acc[m][n][r];
    }
}

// ---------------- flash attention v3 (causal, GQA, balanced pairs, swapped QK^T) ----------------
// Q,K read from fused qkv (row stride QKVN); Vt:(B,NKV,HD,S); O:(B,S,NH,HD) bf16.
#define QBLK 128
#define KVBLK 64
__global__ __launch_bounds__(256, 2) void flash_attn3(const bf16_t* __restrict__ QKV,
                                                      const bf16_t* __restrict__ Vt,
                                                      bf16_t* __restrict__ O) {
  const int pair = blockIdx.x;  // 0..7
  const int h = blockIdx.y, b = blockIdx.z;
  const int g = h >> 2;  // NREP=4
  const int t = threadIdx.x, w = t >> 6, l = t & 63;
  const int lr = l & 15, lg = l >> 4;

  __shared__ __align__(16) char lds[49152];
  char* Ks = lds;                     // [64][128] bf16, 256B rows, swizzled
  char* Vs = lds + 16384;             // [128][64] bf16, 128B rows, swizzled (V^T tile)
  char* Ps = lds + 32768 + w * 4096;  // per-wave [32][64] bf16, 128B rows, swizzled

  const float scale = 0.08838834764831845f;
  const int xm = (lr & 7) << 4;

  for (int phase = 0; phase < 2; phase++) {
    const int qtile = phase ? (15 - pair) : pair;
    const int q0 = qtile * QBLK;
    const int wq = q0 + w * 32;  // this wave's first q row

    // Q -> registers (B-operand layout), scale folded in
    bf16x8 qreg[2][4];
#pragma unroll
    for (int qt = 0; qt < 2; qt++)
#pragma unroll
      for (int kk = 0; kk < 4; kk++) {
        bf16x8 v = *(const bf16x8*)&QKV[((size_t)b * S_ + wq + qt * 16 + lr) * QKVN +
                                        h * HD_ + kk * 32 + lg * 8];
#pragma unroll
        for (int j = 0; j < 8; j++) v[j] = (bf16_t)((float)v[j] * scale);
        qreg[qt][kk] = v;
      }

    float mrun[2] = {-INFINITY, -INFINITY};
    float lrun[2] = {0.f, 0.f};
    f32x4 acc[2][8];
    const f32x4 zero = {0.f, 0.f, 0.f, 0.f};
#pragma unroll
    for (int qt = 0; qt < 2; qt++)
#pragma unroll
      for (int d = 0; d < 8; d++) acc[qt][d] = zero;

    const int nkb = (q0 + QBLK) >> 6;
    for (int kb = 0; kb < nkb; kb++) {
      const int t0 = kb * KVBLK;
      __syncthreads();  // previous tile's readers done
      // ---- stage K [64][128] ----
#pragma unroll
      for (int i = 0; i < 4; i++) {
        const int c = t + i * 256;
        const int row = c >> 4, sl = c & 15;
        bf16x8 kv = *(const bf16x8*)&QKV[((size_t)b * S_ + t0 + row) * QKVN + 4096 +
                                         g * HD_ + sl * 8];
        *(bf16x8*)(Ks + row * 256 + ((sl * 16) ^ ((row & 7) << 4))) = kv;
      }
      // ---- stage V^T [128][64] ----
#pragma unroll
      for (int i = 0; i < 4; i++) {
        const int c = t + i * 256;
        const int row = c >> 3, sl = c & 7;
        bf16x8 vv = *(const bf16x8*)&Vt[(((size_t)b * NKV_ + g) * HD_ + row) * S_ + t0 + sl * 8];
        *(bf16x8*)(Vs + row * 128 + ((sl * 16) ^ ((row & 7) << 4))) = vv;
      }
      __syncthreads();

      if (t0 > wq + 31) continue;  // causal: wave has no work this tile

      // ---- S^T = K @ Q^T : st[n][qt][r] = S[key=t0+n*16+lg*4+r][q=wq+qt*16+lr] ----
      f32x4 st[4][2];
#pragma unroll
      for (int n = 0; n < 4; n++) { st[n][0] = zero; st[n][1] = zero; }
#pragma unroll
      for (int kk = 0; kk < 4; kk++) {
        const int colb = (kk * 64 + lg * 16) ^ xm;
#pragma unroll
        for (int n = 0; n < 4; n++) {
          const bf16x8 ak = *(const bf16x8*)(Ks + (n * 16 + lr) * 256 + colb);
          st[n][0] = __builtin_amdgcn_mfma_f32_16x16x32_bf16(ak, qreg[0][kk], st[n][0], 0, 0, 0);
          st[n][1] = __builtin_amdgcn_mfma_f32_16x16x32_bf16(ak, qreg[1][kk], st[n][1], 0, 0, 0);
        }
      }

      // ---- online softmax: q = wq + qt*16 + lr (per-lane!), keys in-lane ----
      const bool needmask = (t0 + KVBLK - 1 > wq);
#pragma unroll
      for (int qt = 0; qt < 2; qt++) {
        const int q = wq + qt * 16 + lr;
        if (needmask) {
#pragma unroll
          for (int n = 0; n < 4; n++)
#pragma unroll
            for (int r = 0; r < 4; r++)
              if (t0 + n * 16 + lg * 4 + r > q) st[n][qt][r] = -INFINITY;
        }
        float mx = -INFINITY;
#pragma unroll
        for (int n = 0; n < 4; n++)
#pragma unroll
          for (int r = 0; r < 4; r++) mx = fmaxf(mx, st[n][qt][r]);
        mx = fmaxf(mx, __shfl_xor(mx, 16));
        mx = fmaxf(mx, __shfl_xor(mx, 32));
        const float mnew = fmaxf(mrun[qt], mx);
        const float corr = __expf(mrun[qt] - mnew);
        mrun[qt] = mnew;
        float sum = 0.f;
        bf16x4 pk[4];
#pragma unroll
        for (int n = 0; n < 4; n++) {
#pragma unroll
          for (int r = 0; r < 4; r++) {
            const float p = __expf(st[n][qt][r] - mnew);
            sum += p;
            pk[n][r] = (bf16_t)p;
          }
        }
        sum += __shfl_xor(sum, 16);
        sum += __shfl_xor(sum, 32);
        lrun[qt] = lrun[qt] * corr + sum;
        // P^T -> P: lane writes its 4-key packs for its q-column
        {
          char* pbase = Ps + (qt * 16 + lr) * 128;
#pragma unroll
          for (int n = 0; n < 4; n++)
            *(bf16x4*)(pbase + ((n * 32 + lg * 8) ^ xm)) = pk[n];
        }
        // rescale acc: acc rows are q16 = lg*4 + r -> fetch corr from lane lr' = lg*4+r
#pragma unroll
        for (int r = 0; r < 4; r++) {
          const float cb = __shfl(corr, lg * 4 + r);
#pragma unroll
          for (int db = 0; db < 8; db++) acc[qt][db][r] *= cb;
        }
      }

      // ---- O += P @ V  (Ps is per-wave: no barrier needed) ----
#pragma unroll
      for (int kk = 0; kk < 2; kk++) {
        const int colb = (kk * 64 + lg * 16) ^ xm;
        const bf16x8 ap0 = *(const bf16x8*)(Ps + lr * 128 + colb);
        const bf16x8 ap1 = *(const bf16x8*)(Ps + (16 + lr) * 128 + colb);
#pragma unroll
        for (int db = 0; db < 8; db++) {
          const bf16x8 bv = *(const bf16x8*)(Vs + (db * 16 + lr) * 128 + colb);
          acc[0][db] = __builtin_amdgcn_mfma_f32_16x16x32_bf16(ap0, bv, acc[0][db], 0, 0, 0);
          acc[1][db] = __builtin_amdgcn_mfma_f32_16x16x32_bf16(ap1, bv, acc[1][db], 0, 0, 0);
        }
      }
    }

    // ---- epilogue: O = acc / l ----
#pragma unroll
    for (int qt = 0; qt < 2; qt++) {
      const float linv = 1.f / lrun[qt];
#pragma unroll
      for (int r = 0; r < 4; r++) {
        const float li = __shfl(linv, lg * 4 + r);
        const int q = wq + qt * 16 + lg * 4 + r;
#pragma unroll
        for (int db = 0; db < 8; db++)
          O[(((size_t)b * S_ + q) * NH_ + h) * HD_ + db * 16 + lr] = (bf16_t)(acc[qt][db][r] * li);
      }
    }
    __syncthreads();  // protect LDS before next phase restages
  }
}

extern "C" void kernel_launch(void* const* d_in, const int* in_sizes, int n_in,
                              void* d_out, int out_size, void* d_ws, size_t ws_size,
                              hipStream_t stream) {
  const float* x    = (const float*)d_in[0];
  const float* fcos = (const float*)d_in[1];
  const float* fsin = (const float*)d_in[2];
  const float* wq   = (const float*)d_in[3];
  const float* wk   = (const float*)d_in[4];
  const float* wv   = (const float*)d_in[5];
  const float* wo   = (const float*)d_in[6];
  float* out = (float*)d_out;

  char* ws = (char*)d_ws;
  bf16_t* x_bf   = (bf16_t*)(ws);               // 33.5 MB  (4096x4096 bf16)
  bf16_t* wqkvT  = (bf16_t*)(ws + 33554432);    // 50.3 MB  (6144x4096 bf16; later wo^T)
  bf16_t* qkv    = (bf16_t*)(ws + 83886080);    // 50.3 MB  (4096x6144 bf16)
  bf16_t* vt     = (bf16_t*)(ws + 134217728);   // 8.4 MB   (B,NKV,HD,S)
  bf16_t* attn   = (bf16_t*)(ws + 142606336);   // 33.5 MB  (4096x4096 bf16) end ~176 MB

  // allow 128 KiB dynamic LDS on the GEMM kernels (idempotent)
  hipFuncSetAttribute(reinterpret_cast<const void*>(gemm8p<bf16_t>),
                      hipFuncAttributeMaxDynamicSharedMemorySize, 131072);
  hipFuncSetAttribute(reinterpret_cast<const void*>(gemm8p<float>),
                      hipFuncAttributeMaxDynamicSharedMemorySize, 131072);

  // 1. convert x to bf16
  convert_f32_bf16<<<8192, 256, 0, stream>>>(x, x_bf, (size_t)2097152);
  // 2. transpose+convert weights into fused (6144,4096) bf16 W^T
  transpose_convert<<<dim3(128, 128), 256, 0, stream>>>(wq, wqkvT, 4096, 4096);
  transpose_convert<<<dim3(32, 128), 256, 0, stream>>>(wk, wqkvT + (size_t)4096 * 4096, 4096, 1024);
  transpose_convert<<<dim3(32, 128), 256, 0, stream>>>(wv, wqkvT + (size_t)5120 * 4096, 4096, 1024);
  // 3. fused QKV projection: (4096,6144) bf16
  gemm8p<bf16_t><<<dim3(24, 16), 512, 131072, stream>>>(x_bf, wqkvT, qkv, 4096, QKVN, 4096);
  // 4. RoPE in-place on q (cols 0..4095) and k (cols 4096..5119)
  rope_inplace<<<8192, 256, 0, stream>>>(qkv, fcos, fsin, 5, (size_t)2097152);
  rope_inplace<<<2048, 256, 0, stream>>>(qkv + 4096, fcos, fsin, 3, (size_t)524288);
  // 5. V -> (B,NKV,HD,S)
  transpose_v<<<dim3(64, 4, 16), 256, 0, stream>>>(qkv, vt);
  // 6. wo^T into the wqkvT slab (QKV GEMM done reading it)
  transpose_convert<<<dim3(128, 128), 256, 0, stream>>>(wo, wqkvT, 4096, 4096);
  // 7. flash attention v3 (balanced pairs)
  flash_attn3<<<dim3(8, 32, 2), 256, 0, stream>>>(qkv, vt, attn);
  // 8. output projection (f32 out)
  gemm8p<float><<<dim3(16, 16), 512, 131072, stream>>>(attn, wqkvT, out, 4096, 4096, 4096);
}

// Round 6
// 512.432 us; speedup vs baseline: 1.9758x; 1.0361x over previous
//
#include <hip/hip_runtime.h>
#include <hip/hip_bf16.h>
#include <math.h>

typedef __bf16 bf16_t;
typedef __bf16 bf16x4 __attribute__((ext_vector_type(4)));
typedef __bf16 bf16x8 __attribute__((ext_vector_type(8)));
typedef float  f32x4  __attribute__((ext_vector_type(4)));

#define B_   2
#define S_   2048
#define D_   4096
#define NH_  32
#define NKV_ 8
#define HD_  128
#define NREP_ 4
#define QKVN 6144   // fused QKV output width: 4096 q + 1024 k + 1024 v

static __device__ __forceinline__ void gload_lds16(const bf16_t* g, bf16_t* l) {
  __builtin_amdgcn_global_load_lds(
      (const __attribute__((address_space(1))) void*)g,
      (__attribute__((address_space(3))) void*)l, 16, 0, 0);
}

// ---------------- elementwise f32 -> bf16 convert (vectorized) ----------------
__global__ void convert_f32_bf16(const float* __restrict__ in, bf16_t* __restrict__ out,
                                 size_t n8) {
  size_t i = (size_t)blockIdx.x * blockDim.x + threadIdx.x;
  if (i >= n8) return;
  f32x4 a = *(const f32x4*)(in + i * 8);
  f32x4 b = *(const f32x4*)(in + i * 8 + 4);
  bf16x8 o;
  o[0] = (bf16_t)a[0]; o[1] = (bf16_t)a[1]; o[2] = (bf16_t)a[2]; o[3] = (bf16_t)a[3];
  o[4] = (bf16_t)b[0]; o[5] = (bf16_t)b[1]; o[6] = (bf16_t)b[2]; o[7] = (bf16_t)b[3];
  *(bf16x8*)(out + i * 8) = o;
}

// ---------------- transpose + convert: in (R,C) f32 -> out (C,R) bf16 ----------------
__global__ void transpose_convert(const float* __restrict__ in, bf16_t* __restrict__ out,
                                  int R, int C) {
  __shared__ float tile[32][33];
  const int c0 = blockIdx.x * 32, r0 = blockIdx.y * 32;
  const int tc = threadIdx.x & 31, tr = threadIdx.x >> 5;  // tr in 0..7
#pragma unroll
  for (int i = 0; i < 4; i++) {
    int r = tr + i * 8;
    tile[r][tc] = in[(size_t)(r0 + r) * C + c0 + tc];
  }
  __syncthreads();
#pragma unroll
  for (int i = 0; i < 4; i++) {
    int r = tr + i * 8;  // row of OUT tile = col of in
    out[(size_t)(c0 + r) * R + r0 + tc] = (bf16_t)tile[tc][r];
  }
}

// ---------------- transpose V: qkv cols [5120,6144) -> (B,NKV,HD,S) bf16 ----------------
__global__ void transpose_v(const bf16_t* __restrict__ qkv, bf16_t* __restrict__ out) {
  __shared__ bf16_t tile[32][33];
  const int t0 = blockIdx.x * 32, d0 = blockIdx.y * 32;
  const int bg = blockIdx.z, b = bg / NKV_, g = bg % NKV_;
  const bf16_t* ibase = qkv + (size_t)b * S_ * QKVN + 5120 + g * HD_;
  bf16_t* obase = out + ((size_t)b * NKV_ + g) * (size_t)HD_ * S_;
  const int tc = threadIdx.x & 31, tr = threadIdx.x >> 5;
#pragma unroll
  for (int i = 0; i < 4; i++) {
    int t = t0 + tr + i * 8;
    tile[tr + i * 8][tc] = ibase[(size_t)t * QKVN + d0 + tc];
  }
  __syncthreads();
#pragma unroll
  for (int i = 0; i < 4; i++) {
    int d = d0 + tr + i * 8;
    obase[(size_t)d * S_ + t0 + tc] = tile[tc][tr + i * 8];
  }
}

// ---------------- RoPE in-place on qkv buffer (row stride QKVN) ----------------
__global__ void rope_inplace(bf16_t* __restrict__ x, const float* __restrict__ cosT,
                             const float* __restrict__ sinT, int lgh, size_t nchunks) {
  size_t i = (size_t)blockIdx.x * blockDim.x + threadIdx.x;
  if (i >= nchunks) return;
  const int d8 = (int)(i & 15);
  const int h = (int)((i >> 4) & ((1u << lgh) - 1));
  const size_t pos = i >> (4 + lgh);
  const int s = (int)(pos & (S_ - 1));
  bf16_t* p = x + pos * QKVN + h * HD_ + d8 * 8;
  bf16x8 v = *(bf16x8*)p;
  f32x4 c  = *(const f32x4*)(cosT + (size_t)s * 64 + d8 * 4);
  f32x4 sn = *(const f32x4*)(sinT + (size_t)s * 64 + d8 * 4);
  bf16x8 o;
#pragma unroll
  for (int j = 0; j < 4; j++) {
    float re = (float)v[2 * j], im = (float)v[2 * j + 1];
    o[2 * j]     = (bf16_t)(re * c[j] - im * sn[j]);
    o[2 * j + 1] = (bf16_t)(re * sn[j] + im * c[j]);
  }
  *(bf16x8*)p = o;
}

// ---------------- 256x256 NT GEMM, BK=64, read-ahead 4-phase pipeline ----------------
// C(M,N) = A(M,K) @ Bt(N,K)^T. 512 threads = 8 waves (2M x 4N), wave tile 128x64.
// LDS: 2 K-tile dbufs x (A[256][64] + B[256][64]) bf16 = 128 KiB dynamic.
// Register read-ahead: phase p issues ds_reads of phase p+1's A-frags (aE/aO dbuf);
// B-frags read once per K-tile at p0. One raw barrier per phase; counted vmcnt(4)
// at p2-end (ledger: kt c+1's last issue at (c,0); issues after = 4).
template <typename OutT>
__global__ __launch_bounds__(512, 2) void gemm8p(const bf16_t* __restrict__ Ag,
                                                 const bf16_t* __restrict__ Bg,
                                                 OutT* __restrict__ C,
                                                 int M, int N, int K) {
  extern __shared__ __align__(16) bf16_t lds[];  // 2 * 32768 elements
  const int t = threadIdx.x;
  const int w = t >> 6, l = t & 63;
  const int wm = w >> 2, wn = w & 3;
  const int lr = l & 15, lg = l >> 4;

  // XCD-chunked swizzle of flattened block id (grid % 8 == 0 for all our launches)
  const int nbx = gridDim.x;
  const int nwg = nbx * gridDim.y;
  const int bid = blockIdx.y * nbx + blockIdx.x;
  const int cpx = nwg >> 3;
  const int sid = (bid & 7) * cpx + (bid >> 3);
  const int n0 = (sid % nbx) * 256;
  const int m0 = (sid / nbx) * 256;

  const int srow = t >> 3;                            // 0..63 (row within quarter)
  const int colsw = ((t & 7) ^ (srow & 7)) * 8;       // pre-swizzled source col (elements)
  const int xsw = (lr & 7) * 8;                       // read-side swizzle (elements)

  auto stageA = [&](int db, int k0, int q) {
    gload_lds16(Ag + (size_t)(m0 + q * 64 + srow) * K + k0 + colsw,
                lds + db * 32768 + q * 4096 + t * 8);
  };
  auto stageB = [&](int db, int k0, int q) {
    gload_lds16(Bg + (size_t)(n0 + q * 64 + srow) * K + k0 + colsw,
                lds + db * 32768 + 16384 + q * 4096 + t * 8);
  };

  f32x4 acc[8][4];
  const f32x4 zero = {0.f, 0.f, 0.f, 0.f};
#pragma unroll
  for (int m = 0; m < 8; m++)
#pragma unroll
    for (int n = 0; n < 4; n++) acc[m][n] = zero;

  bf16x8 bfrag[4][2];
  bf16x8 aE[4], aO[4];

  auto readA = [&](bf16x8* dst, const bf16_t* base, int p) {
    const bf16_t* r0 = base + (wm * 128 + (2 * p) * 16 + lr) * 64;
    const bf16_t* r1 = base + (wm * 128 + (2 * p + 1) * 16 + lr) * 64;
    dst[0] = *(const bf16x8*)(r0 + ((lg * 8) ^ xsw));
    dst[1] = *(const bf16x8*)(r0 + ((32 + lg * 8) ^ xsw));
    dst[2] = *(const bf16x8*)(r1 + ((lg * 8) ^ xsw));
    dst[3] = *(const bf16x8*)(r1 + ((32 + lg * 8) ^ xsw));
  };
  auto readB = [&](const bf16_t* pB) {
#pragma unroll
    for (int n = 0; n < 4; n++)
#pragma unroll
      for (int ks = 0; ks < 2; ks++)
        bfrag[n][ks] =
            *(const bf16x8*)(pB + (wn * 64 + n * 16 + lr) * 64 + ((ks * 32 + lg * 8) ^ xsw));
  };
  // MFMA cluster for phase p; dependency distance 8 between RAW pairs.
  auto mfmaPhase = [&](int p, const bf16x8* a) {
    __builtin_amdgcn_s_setprio(1);
#pragma unroll
    for (int n = 0; n < 4; n++)
      acc[2 * p][n] = __builtin_amdgcn_mfma_f32_16x16x32_bf16(a[0], bfrag[n][0], acc[2 * p][n], 0, 0, 0);
#pragma unroll
    for (int n = 0; n < 4; n++)
      acc[2 * p + 1][n] = __builtin_amdgcn_mfma_f32_16x16x32_bf16(a[2], bfrag[n][0], acc[2 * p + 1][n], 0, 0, 0);
#pragma unroll
    for (int n = 0; n < 4; n++)
      acc[2 * p][n] = __builtin_amdgcn_mfma_f32_16x16x32_bf16(a[1], bfrag[n][1], acc[2 * p][n], 0, 0, 0);
#pragma unroll
    for (int n = 0; n < 4; n++)
      acc[2 * p + 1][n] = __builtin_amdgcn_mfma_f32_16x16x32_bf16(a[3], bfrag[n][1], acc[2 * p + 1][n], 0, 0, 0);
    __builtin_amdgcn_s_setprio(0);
  };

  const int KT = K >> 6;  // K-tiles of 64

  // ---- prologue: kt0 full (8), B[1] (4), A[1].q0q2 (2) ----
#pragma unroll
  for (int q = 0; q < 4; q++) stageA(0, 0, q);
#pragma unroll
  for (int q = 0; q < 4; q++) stageB(0, 0, q);
#pragma unroll
  for (int q = 0; q < 4; q++) stageB(1, 64, q);
  stageA(1, 64, 0);
  stageA(1, 64, 2);
  asm volatile("s_waitcnt vmcnt(6)" ::: "memory");  // kt0 arrived; 6 in flight
  __builtin_amdgcn_s_barrier();
  __builtin_amdgcn_sched_barrier(0);
  readA(aE, lds, 0);  // A[0].p0 frags

  for (int c = 0; c < KT; ++c) {
    const int d = c & 1;
    const bf16_t* pA = lds + d * 32768;
    const bf16_t* pB = pA + 16384;
    const bool st2 = (c + 2) < KT;
    const int k2 = (c + 2) << 6;

    // ---- phase 0: B[c] + A[c].p1 reads; stage A[c+1].q1q3; MFMA p0 ----
    readB(pB);
    readA(aO, pA, 1);
    if (c + 1 < KT) { stageA(1 - d, (c + 1) << 6, 1); stageA(1 - d, (c + 1) << 6, 3); }
    mfmaPhase(0, aE);
    __builtin_amdgcn_s_barrier();
    __builtin_amdgcn_sched_barrier(0);

    // ---- phase 1: A[c].p2 reads; stage B[c+2].q01; MFMA p1 ----
    readA(aE, pA, 2);
    if (st2) { stageB(d, k2, 0); stageB(d, k2, 1); }
    mfmaPhase(1, aO);
    __builtin_amdgcn_s_barrier();
    __builtin_amdgcn_sched_barrier(0);

    // ---- phase 2: A[c].p3 reads; stage B[c+2].q23; MFMA p2; vmcnt ----
    readA(aO, pA, 3);
    if (st2) { stageB(d, k2, 2); stageB(d, k2, 3); }
    mfmaPhase(2, aE);
    if (st2) asm volatile("s_waitcnt vmcnt(4)" ::: "memory");  // kt c+1 arrived
    else     asm volatile("s_waitcnt vmcnt(0)" ::: "memory");
    __builtin_amdgcn_s_barrier();
    __builtin_amdgcn_sched_barrier(0);

    // ---- phase 3: A[c+1].p0 reads (other dbuf); stage A[c+2].q0q2; MFMA p3 ----
    if (c + 1 < KT) readA(aE, lds + (1 - d) * 32768, 0);
    if (st2) { stageA(d, k2, 0); stageA(d, k2, 2); }
    mfmaPhase(3, aO);
    __builtin_amdgcn_s_barrier();
    __builtin_amdgcn_sched_barrier(0);
  }

  // ---- epilogue ----
#pragma unroll
  for (int m = 0; m < 8; m++)
#pragma unroll
    for (int n = 0; n < 4; n++) {
      const int row = m0 + wm * 128 + m * 16 + lg * 4;
      const int col = n0 + wn * 64 + n * 16 + lr;
#pragma unroll
      for (int r = 0; r < 4; r++) C[(size_t)(row + r) * N + col] = (OutT)acc[m][n][r];
    }
}

// ---------------- flash attention v3 (causal, GQA, balanced pairs, swapped QK^T) ----------------
// Q,K read from fused qkv (row stride QKVN); Q-RoPE fused into the Q-load.
// Vt:(B,NKV,HD,S); O:(B,S,NH,HD) bf16.
#define QBLK 128
#define KVBLK 64
__global__ __launch_bounds__(256, 2) void flash_attn3(const bf16_t* __restrict__ QKV,
                                                      const bf16_t* __restrict__ Vt,
                                                      const float* __restrict__ cosT,
                                                      const float* __restrict__ sinT,
                                                      bf16_t* __restrict__ O) {
  const int pair = blockIdx.x;  // 0..7
  const int h = blockIdx.y, b = blockIdx.z;
  const int g = h >> 2;  // NREP=4
  const int t = threadIdx.x, w = t >> 6, l = t & 63;
  const int lr = l & 15, lg = l >> 4;

  __shared__ __align__(16) char lds[49152];
  char* Ks = lds;                     // [64][128] bf16, 256B rows, swizzled
  char* Vs = lds + 16384;             // [128][64] bf16, 128B rows, swizzled (V^T tile)
  char* Ps = lds + 32768 + w * 4096;  // per-wave [32][64] bf16, 128B rows, swizzled

  const float scale = 0.08838834764831845f;
  const int xm = (lr & 7) << 4;

  for (int phase = 0; phase < 2; phase++) {
    const int qtile = phase ? (15 - pair) : pair;
    const int q0 = qtile * QBLK;
    const int wq = q0 + w * 32;  // this wave's first q row

    // Q -> registers (B-operand layout), RoPE + scale fused
    bf16x8 qreg[2][4];
#pragma unroll
    for (int qt = 0; qt < 2; qt++) {
      const int s = wq + qt * 16 + lr;  // sequence position (< S_)
#pragma unroll
      for (int kk = 0; kk < 4; kk++) {
        bf16x8 v = *(const bf16x8*)&QKV[((size_t)b * S_ + s) * QKVN +
                                        h * HD_ + kk * 32 + lg * 8];
        f32x4 c4 = *(const f32x4*)(cosT + (size_t)s * 64 + kk * 16 + lg * 4);
        f32x4 s4 = *(const f32x4*)(sinT + (size_t)s * 64 + kk * 16 + lg * 4);
        bf16x8 o;
#pragma unroll
        for (int j = 0; j < 4; j++) {
          float re = (float)v[2 * j], im = (float)v[2 * j + 1];
          o[2 * j]     = (bf16_t)((re * c4[j] - im * s4[j]) * scale);
          o[2 * j + 1] = (bf16_t)((re * s4[j] + im * c4[j]) * scale);
        }
        qreg[qt][kk] = o;
      }
    }

    float mrun[2] = {-INFINITY, -INFINITY};
    float lrun[2] = {0.f, 0.f};
    f32x4 acc[2][8];
    const f32x4 zero = {0.f, 0.f, 0.f, 0.f};
#pragma unroll
    for (int qt = 0; qt < 2; qt++)
#pragma unroll
      for (int d = 0; d < 8; d++) acc[qt][d] = zero;

    const int nkb = (q0 + QBLK) >> 6;
    for (int kb = 0; kb < nkb; kb++) {
      const int t0 = kb * KVBLK;
      __syncthreads();  // previous tile's readers done
      // ---- stage K [64][128] ----
#pragma unroll
      for (int i = 0; i < 4; i++) {
        const int c = t + i * 256;
        const int row = c >> 4, sl = c & 15;
        bf16x8 kv = *(const bf16x8*)&QKV[((size_t)b * S_ + t0 + row) * QKVN + 4096 +
                                         g * HD_ + sl * 8];
        *(bf16x8*)(Ks + row * 256 + ((sl * 16) ^ ((row & 7) << 4))) = kv;
      }
      // ---- stage V^T [128][64] ----
#pragma unroll
      for (int i = 0; i < 4; i++) {
        const int c = t + i * 256;
        const int row = c >> 3, sl = c & 7;
        bf16x8 vv = *(const bf16x8*)&Vt[(((size_t)b * NKV_ + g) * HD_ + row) * S_ + t0 + sl * 8];
        *(bf16x8*)(Vs + row * 128 + ((sl * 16) ^ ((row & 7) << 4))) = vv;
      }
      __syncthreads();

      if (t0 > wq + 31) continue;  // causal: wave has no work this tile

      // ---- S^T = K @ Q^T : st[n][qt][r] = S[key=t0+n*16+lg*4+r][q=wq+qt*16+lr] ----
      f32x4 st[4][2];
#pragma unroll
      for (int n = 0; n < 4; n++) { st[n][0] = zero; st[n][1] = zero; }
#pragma unroll
      for (int kk = 0; kk < 4; kk++) {
        const int colb = (kk * 64 + lg * 16) ^ xm;
#pragma unroll
        for (int n = 0; n < 4; n++) {
          const bf16x8 ak = *(const bf16x8*)(Ks + (n * 16 + lr) * 256 + colb);
          st[n][0] = __builtin_amdgcn_mfma_f32_16x16x32_bf16(ak, qreg[0][kk], st[n][0], 0, 0, 0);
          st[n][1] = __builtin_amdgcn_mfma_f32_16x16x32_bf16(ak, qreg[1][kk], st[n][1], 0, 0, 0);
        }
      }

      // ---- online softmax: q = wq + qt*16 + lr (per-lane!), keys in-lane ----
      const bool needmask = (t0 + KVBLK - 1 > wq);
#pragma unroll
      for (int qt = 0; qt < 2; qt++) {
        const int q = wq + qt * 16 + lr;
        if (needmask) {
#pragma unroll
          for (int n = 0; n < 4; n++)
#pragma unroll
            for (int r = 0; r < 4; r++)
              if (t0 + n * 16 + lg * 4 + r > q) st[n][qt][r] = -INFINITY;
        }
        float mx = -INFINITY;
#pragma unroll
        for (int n = 0; n < 4; n++)
#pragma unroll
          for (int r = 0; r < 4; r++) mx = fmaxf(mx, st[n][qt][r]);
        mx = fmaxf(mx, __shfl_xor(mx, 16));
        mx = fmaxf(mx, __shfl_xor(mx, 32));
        const float mnew = fmaxf(mrun[qt], mx);
        const float corr = __expf(mrun[qt] - mnew);
        mrun[qt] = mnew;
        float sum = 0.f;
        bf16x4 pk[4];
#pragma unroll
        for (int n = 0; n < 4; n++) {
#pragma unroll
          for (int r = 0; r < 4; r++) {
            const float p = __expf(st[n][qt][r] - mnew);
            sum += p;
            pk[n][r] = (bf16_t)p;
          }
        }
        sum += __shfl_xor(sum, 16);
        sum += __shfl_xor(sum, 32);
        lrun[qt] = lrun[qt] * corr + sum;
        // P^T -> P: lane writes its 4-key packs for its q-column
        {
          char* pbase = Ps + (qt * 16 + lr) * 128;
#pragma unroll
          for (int n = 0; n < 4; n++)
            *(bf16x4*)(pbase + ((n * 32 + lg * 8) ^ xm)) = pk[n];
        }
        // rescale acc: acc rows are q16 = lg*4 + r -> fetch corr from lane lr' = lg*4+r
#pragma unroll
        for (int r = 0; r < 4; r++) {
          const float cb = __shfl(corr, lg * 4 + r);
#pragma unroll
          for (int db = 0; db < 8; db++) acc[qt][db][r] *= cb;
        }
      }

      // ---- O += P @ V  (Ps is per-wave: no barrier needed) ----
#pragma unroll
      for (int kk = 0; kk < 2; kk++) {
        const int colb = (kk * 64 + lg * 16) ^ xm;
        const bf16x8 ap0 = *(const bf16x8*)(Ps + lr * 128 + colb);
        const bf16x8 ap1 = *(const bf16x8*)(Ps + (16 + lr) * 128 + colb);
#pragma unroll
        for (int db = 0; db < 8; db++) {
          const bf16x8 bv = *(const bf16x8*)(Vs + (db * 16 + lr) * 128 + colb);
          acc[0][db] = __builtin_amdgcn_mfma_f32_16x16x32_bf16(ap0, bv, acc[0][db], 0, 0, 0);
          acc[1][db] = __builtin_amdgcn_mfma_f32_16x16x32_bf16(ap1, bv, acc[1][db], 0, 0, 0);
        }
      }
    }

    // ---- epilogue: O = acc / l ----
#pragma unroll
    for (int qt = 0; qt < 2; qt++) {
      const float linv = 1.f / lrun[qt];
#pragma unroll
      for (int r = 0; r < 4; r++) {
        const float li = __shfl(linv, lg * 4 + r);
        const int q = wq + qt * 16 + lg * 4 + r;
#pragma unroll
        for (int db = 0; db < 8; db++)
          O[(((size_t)b * S_ + q) * NH_ + h) * HD_ + db * 16 + lr] = (bf16_t)(acc[qt][db][r] * li);
      }
    }
    __syncthreads();  // protect LDS before next phase restages
  }
}

extern "C" void kernel_launch(void* const* d_in, const int* in_sizes, int n_in,
                              void* d_out, int out_size, void* d_ws, size_t ws_size,
                              hipStream_t stream) {
  const float* x    = (const float*)d_in[0];
  const float* fcos = (const float*)d_in[1];
  const float* fsin = (const float*)d_in[2];
  const float* wq   = (const float*)d_in[3];
  const float* wk   = (const float*)d_in[4];
  const float* wv   = (const float*)d_in[5];
  const float* wo   = (const float*)d_in[6];
  float* out = (float*)d_out;

  char* ws = (char*)d_ws;
  bf16_t* x_bf   = (bf16_t*)(ws);               // 33.5 MB  (4096x4096 bf16)
  bf16_t* wqkvT  = (bf16_t*)(ws + 33554432);    // 50.3 MB  (6144x4096 bf16; later wo^T)
  bf16_t* qkv    = (bf16_t*)(ws + 83886080);    // 50.3 MB  (4096x6144 bf16)
  bf16_t* vt     = (bf16_t*)(ws + 134217728);   // 8.4 MB   (B,NKV,HD,S)
  bf16_t* attn   = (bf16_t*)(ws + 142606336);   // 33.5 MB  (4096x4096 bf16) end ~176 MB

  // allow 128 KiB dynamic LDS on the GEMM kernels (idempotent)
  hipFuncSetAttribute(reinterpret_cast<const void*>(gemm8p<bf16_t>),
                      hipFuncAttributeMaxDynamicSharedMemorySize, 131072);
  hipFuncSetAttribute(reinterpret_cast<const void*>(gemm8p<float>),
                      hipFuncAttributeMaxDynamicSharedMemorySize, 131072);

  // 1. convert x to bf16
  convert_f32_bf16<<<8192, 256, 0, stream>>>(x, x_bf, (size_t)2097152);
  // 2. transpose+convert weights into fused (6144,4096) bf16 W^T
  transpose_convert<<<dim3(128, 128), 256, 0, stream>>>(wq, wqkvT, 4096, 4096);
  transpose_convert<<<dim3(32, 128), 256, 0, stream>>>(wk, wqkvT + (size_t)4096 * 4096, 4096, 1024);
  transpose_convert<<<dim3(32, 128), 256, 0, stream>>>(wv, wqkvT + (size_t)5120 * 4096, 4096, 1024);
  // 3. fused QKV projection: (4096,6144) bf16
  gemm8p<bf16_t><<<dim3(24, 16), 512, 131072, stream>>>(x_bf, wqkvT, qkv, 4096, QKVN, 4096);
  // 4. RoPE in-place on k only (q-rope fused into flash)
  rope_inplace<<<2048, 256, 0, stream>>>(qkv + 4096, fcos, fsin, 3, (size_t)524288);
  // 5. V -> (B,NKV,HD,S)
  transpose_v<<<dim3(64, 4, 16), 256, 0, stream>>>(qkv, vt);
  // 6. wo^T into the wqkvT slab (QKV GEMM done reading it)
  transpose_convert<<<dim3(128, 128), 256, 0, stream>>>(wo, wqkvT, 4096, 4096);
  // 7. flash attention v3 (balanced pairs, fused Q-rope)
  flash_attn3<<<dim3(8, 32, 2), 256, 0, stream>>>(qkv, vt, fcos, fsin, attn);
  // 8. output projection (f32 out)
  gemm8p<float><<<dim3(16, 16), 512, 131072, stream>>>(attn, wqkvT, out, 4096, 4096, 4096);
}

// Round 7
// 510.984 us; speedup vs baseline: 1.9814x; 1.0028x over previous
//
#include <hip/hip_runtime.h>
#include <hip/hip_bf16.h>
#include <math.h>

typedef __bf16 bf16_t;
typedef __bf16 bf16x4 __attribute__((ext_vector_type(4)));
typedef __bf16 bf16x8 __attribute__((ext_vector_type(8)));
typedef float  f32x4  __attribute__((ext_vector_type(4)));

#define B_   2
#define S_   2048
#define D_   4096
#define NH_  32
#define NKV_ 8
#define HD_  128
#define NREP_ 4
#define QKVN 6144   // fused QKV output width: 4096 q + 1024 k + 1024 v

static __device__ __forceinline__ void gload_lds16(const bf16_t* g, bf16_t* l) {
  __builtin_amdgcn_global_load_lds(
      (const __attribute__((address_space(1))) void*)g,
      (__attribute__((address_space(3))) void*)l, 16, 0, 0);
}

// ---------------- elementwise f32 -> bf16 convert (vectorized) ----------------
__global__ void convert_f32_bf16(const float* __restrict__ in, bf16_t* __restrict__ out,
                                 size_t n8) {
  size_t i = (size_t)blockIdx.x * blockDim.x + threadIdx.x;
  if (i >= n8) return;
  f32x4 a = *(const f32x4*)(in + i * 8);
  f32x4 b = *(const f32x4*)(in + i * 8 + 4);
  bf16x8 o;
  o[0] = (bf16_t)a[0]; o[1] = (bf16_t)a[1]; o[2] = (bf16_t)a[2]; o[3] = (bf16_t)a[3];
  o[4] = (bf16_t)b[0]; o[5] = (bf16_t)b[1]; o[6] = (bf16_t)b[2]; o[7] = (bf16_t)b[3];
  *(bf16x8*)(out + i * 8) = o;
}

// ---------------- transpose + convert: in (R,C) f32 -> out (C,R) bf16 ----------------
__global__ void transpose_convert(const float* __restrict__ in, bf16_t* __restrict__ out,
                                  int R, int C) {
  __shared__ float tile[32][33];
  const int c0 = blockIdx.x * 32, r0 = blockIdx.y * 32;
  const int tc = threadIdx.x & 31, tr = threadIdx.x >> 5;  // tr in 0..7
#pragma unroll
  for (int i = 0; i < 4; i++) {
    int r = tr + i * 8;
    tile[r][tc] = in[(size_t)(r0 + r) * C + c0 + tc];
  }
  __syncthreads();
#pragma unroll
  for (int i = 0; i < 4; i++) {
    int r = tr + i * 8;  // row of OUT tile = col of in
    out[(size_t)(c0 + r) * R + r0 + tc] = (bf16_t)tile[tc][r];
  }
}

// ---------------- transpose V: qkv cols [5120,6144) -> (B,NKV,HD,S) bf16 ----------------
__global__ void transpose_v(const bf16_t* __restrict__ qkv, bf16_t* __restrict__ out) {
  __shared__ bf16_t tile[32][33];
  const int t0 = blockIdx.x * 32, d0 = blockIdx.y * 32;
  const int bg = blockIdx.z, b = bg / NKV_, g = bg % NKV_;
  const bf16_t* ibase = qkv + (size_t)b * S_ * QKVN + 5120 + g * HD_;
  bf16_t* obase = out + ((size_t)b * NKV_ + g) * (size_t)HD_ * S_;
  const int tc = threadIdx.x & 31, tr = threadIdx.x >> 5;
#pragma unroll
  for (int i = 0; i < 4; i++) {
    int t = t0 + tr + i * 8;
    tile[tr + i * 8][tc] = ibase[(size_t)t * QKVN + d0 + tc];
  }
  __syncthreads();
#pragma unroll
  for (int i = 0; i < 4; i++) {
    int d = d0 + tr + i * 8;
    obase[(size_t)d * S_ + t0 + tc] = tile[tc][tr + i * 8];
  }
}

// ---------------- RoPE in-place on qkv buffer (row stride QKVN) ----------------
__global__ void rope_inplace(bf16_t* __restrict__ x, const float* __restrict__ cosT,
                             const float* __restrict__ sinT, int lgh, size_t nchunks) {
  size_t i = (size_t)blockIdx.x * blockDim.x + threadIdx.x;
  if (i >= nchunks) return;
  const int d8 = (int)(i & 15);
  const int h = (int)((i >> 4) & ((1u << lgh) - 1));
  const size_t pos = i >> (4 + lgh);
  const int s = (int)(pos & (S_ - 1));
  bf16_t* p = x + pos * QKVN + h * HD_ + d8 * 8;
  bf16x8 v = *(bf16x8*)p;
  f32x4 c  = *(const f32x4*)(cosT + (size_t)s * 64 + d8 * 4);
  f32x4 sn = *(const f32x4*)(sinT + (size_t)s * 64 + d8 * 4);
  bf16x8 o;
#pragma unroll
  for (int j = 0; j < 4; j++) {
    float re = (float)v[2 * j], im = (float)v[2 * j + 1];
    o[2 * j]     = (bf16_t)(re * c[j] - im * sn[j]);
    o[2 * j + 1] = (bf16_t)(re * sn[j] + im * c[j]);
  }
  *(bf16x8*)p = o;
}

// ---------------- 256x256 NT GEMM, BK=64, read-ahead 4-phase pipeline ----------------
// (unchanged from round 6)
template <typename OutT>
__global__ __launch_bounds__(512, 2) void gemm8p(const bf16_t* __restrict__ Ag,
                                                 const bf16_t* __restrict__ Bg,
                                                 OutT* __restrict__ C,
                                                 int M, int N, int K) {
  extern __shared__ __align__(16) bf16_t lds[];  // 2 * 32768 elements
  const int t = threadIdx.x;
  const int w = t >> 6, l = t & 63;
  const int wm = w >> 2, wn = w & 3;
  const int lr = l & 15, lg = l >> 4;

  const int nbx = gridDim.x;
  const int nwg = nbx * gridDim.y;
  const int bid = blockIdx.y * nbx + blockIdx.x;
  const int cpx = nwg >> 3;
  const int sid = (bid & 7) * cpx + (bid >> 3);
  const int n0 = (sid % nbx) * 256;
  const int m0 = (sid / nbx) * 256;

  const int srow = t >> 3;                            // 0..63 (row within quarter)
  const int colsw = ((t & 7) ^ (srow & 7)) * 8;       // pre-swizzled source col (elements)
  const int xsw = (lr & 7) * 8;                       // read-side swizzle (elements)

  auto stageA = [&](int db, int k0, int q) {
    gload_lds16(Ag + (size_t)(m0 + q * 64 + srow) * K + k0 + colsw,
                lds + db * 32768 + q * 4096 + t * 8);
  };
  auto stageB = [&](int db, int k0, int q) {
    gload_lds16(Bg + (size_t)(n0 + q * 64 + srow) * K + k0 + colsw,
                lds + db * 32768 + 16384 + q * 4096 + t * 8);
  };

  f32x4 acc[8][4];
  const f32x4 zero = {0.f, 0.f, 0.f, 0.f};
#pragma unroll
  for (int m = 0; m < 8; m++)
#pragma unroll
    for (int n = 0; n < 4; n++) acc[m][n] = zero;

  bf16x8 bfrag[4][2];
  bf16x8 aE[4], aO[4];

  auto readA = [&](bf16x8* dst, const bf16_t* base, int p) {
    const bf16_t* r0 = base + (wm * 128 + (2 * p) * 16 + lr) * 64;
    const bf16_t* r1 = base + (wm * 128 + (2 * p + 1) * 16 + lr) * 64;
    dst[0] = *(const bf16x8*)(r0 + ((lg * 8) ^ xsw));
    dst[1] = *(const bf16x8*)(r0 + ((32 + lg * 8) ^ xsw));
    dst[2] = *(const bf16x8*)(r1 + ((lg * 8) ^ xsw));
    dst[3] = *(const bf16x8*)(r1 + ((32 + lg * 8) ^ xsw));
  };
  auto readB = [&](const bf16_t* pB) {
#pragma unroll
    for (int n = 0; n < 4; n++)
#pragma unroll
      for (int ks = 0; ks < 2; ks++)
        bfrag[n][ks] =
            *(const bf16x8*)(pB + (wn * 64 + n * 16 + lr) * 64 + ((ks * 32 + lg * 8) ^ xsw));
  };
  auto mfmaPhase = [&](int p, const bf16x8* a) {
    __builtin_amdgcn_s_setprio(1);
#pragma unroll
    for (int n = 0; n < 4; n++)
      acc[2 * p][n] = __builtin_amdgcn_mfma_f32_16x16x32_bf16(a[0], bfrag[n][0], acc[2 * p][n], 0, 0, 0);
#pragma unroll
    for (int n = 0; n < 4; n++)
      acc[2 * p + 1][n] = __builtin_amdgcn_mfma_f32_16x16x32_bf16(a[2], bfrag[n][0], acc[2 * p + 1][n], 0, 0, 0);
#pragma unroll
    for (int n = 0; n < 4; n++)
      acc[2 * p][n] = __builtin_amdgcn_mfma_f32_16x16x32_bf16(a[1], bfrag[n][1], acc[2 * p][n], 0, 0, 0);
#pragma unroll
    for (int n = 0; n < 4; n++)
      acc[2 * p + 1][n] = __builtin_amdgcn_mfma_f32_16x16x32_bf16(a[3], bfrag[n][1], acc[2 * p + 1][n], 0, 0, 0);
    __builtin_amdgcn_s_setprio(0);
  };

  const int KT = K >> 6;  // K-tiles of 64

#pragma unroll
  for (int q = 0; q < 4; q++) stageA(0, 0, q);
#pragma unroll
  for (int q = 0; q < 4; q++) stageB(0, 0, q);
#pragma unroll
  for (int q = 0; q < 4; q++) stageB(1, 64, q);
  stageA(1, 64, 0);
  stageA(1, 64, 2);
  asm volatile("s_waitcnt vmcnt(6)" ::: "memory");
  __builtin_amdgcn_s_barrier();
  __builtin_amdgcn_sched_barrier(0);
  readA(aE, lds, 0);

  for (int c = 0; c < KT; ++c) {
    const int d = c & 1;
    const bf16_t* pA = lds + d * 32768;
    const bf16_t* pB = pA + 16384;
    const bool st2 = (c + 2) < KT;
    const int k2 = (c + 2) << 6;

    readB(pB);
    readA(aO, pA, 1);
    if (c + 1 < KT) { stageA(1 - d, (c + 1) << 6, 1); stageA(1 - d, (c + 1) << 6, 3); }
    mfmaPhase(0, aE);
    __builtin_amdgcn_s_barrier();
    __builtin_amdgcn_sched_barrier(0);

    readA(aE, pA, 2);
    if (st2) { stageB(d, k2, 0); stageB(d, k2, 1); }
    mfmaPhase(1, aO);
    __builtin_amdgcn_s_barrier();
    __builtin_amdgcn_sched_barrier(0);

    readA(aO, pA, 3);
    if (st2) { stageB(d, k2, 2); stageB(d, k2, 3); }
    mfmaPhase(2, aE);
    if (st2) asm volatile("s_waitcnt vmcnt(4)" ::: "memory");
    else     asm volatile("s_waitcnt vmcnt(0)" ::: "memory");
    __builtin_amdgcn_s_barrier();
    __builtin_amdgcn_sched_barrier(0);

    if (c + 1 < KT) readA(aE, lds + (1 - d) * 32768, 0);
    if (st2) { stageA(d, k2, 0); stageA(d, k2, 2); }
    mfmaPhase(3, aO);
    __builtin_amdgcn_s_barrier();
    __builtin_amdgcn_sched_barrier(0);
  }

#pragma unroll
  for (int m = 0; m < 8; m++)
#pragma unroll
    for (int n = 0; n < 4; n++) {
      const int row = m0 + wm * 128 + m * 16 + lg * 4;
      const int col = n0 + wn * 64 + n * 16 + lr;
#pragma unroll
      for (int r = 0; r < 4; r++) C[(size_t)(row + r) * N + col] = (OutT)acc[m][n][r];
    }
}

// ---------------- flash attention v4 (causal, GQA, balanced pairs, swapped QK^T) ----------------
// Q,K from fused qkv (Q-RoPE fused); Vt:(B,NKV,HD,S); O:(B,S,NH,HD) bf16.
// v4: T14 async-STAGE (reg-prefetch next K/V tile during compute, ds_write after barrier)
//     + T13 defer-max rescale (skip O-rescale when __all(mx <= mrun + 8)).
#define QBLK 128
#define KVBLK 64
__global__ __launch_bounds__(256, 2) void flash_attn4(const bf16_t* __restrict__ QKV,
                                                      const bf16_t* __restrict__ Vt,
                                                      const float* __restrict__ cosT,
                                                      const float* __restrict__ sinT,
                                                      bf16_t* __restrict__ O) {
  const int pair = blockIdx.x;  // 0..7
  const int h = blockIdx.y, b = blockIdx.z;
  const int g = h >> 2;  // NREP=4
  const int t = threadIdx.x, w = t >> 6, l = t & 63;
  const int lr = l & 15, lg = l >> 4;

  __shared__ __align__(16) char lds[49152];
  char* Ks = lds;                     // [64][128] bf16, 256B rows, swizzled
  char* Vs = lds + 16384;             // [128][64] bf16, 128B rows, swizzled (V^T tile)
  char* Ps = lds + 32768 + w * 4096;  // per-wave [32][64] bf16, 128B rows, swizzled

  const float scale = 0.08838834764831845f;
  const int xm = (lr & 7) << 4;

  // T14 staging registers + helpers
  bf16x8 kpre[4], vpre[4];
  const int krow = t >> 4, ksl = t & 15;          // K: 64 rows x 16 slots
  const int vrow = t >> 3, vsl = t & 7;           // V^T: 128 rows x 8 slots
  auto loadKV = [&](int t0) {
#pragma unroll
    for (int i = 0; i < 4; i++)
      kpre[i] = *(const bf16x8*)&QKV[((size_t)b * S_ + t0 + krow + i * 16) * QKVN + 4096 +
                                     g * HD_ + ksl * 8];
#pragma unroll
    for (int i = 0; i < 4; i++)
      vpre[i] = *(const bf16x8*)&Vt[(((size_t)b * NKV_ + g) * HD_ + vrow + i * 32) * S_ +
                                    t0 + vsl * 8];
  };
  auto writeKV = [&]() {
#pragma unroll
    for (int i = 0; i < 4; i++) {
      const int row = krow + i * 16;
      *(bf16x8*)(Ks + row * 256 + ((ksl * 16) ^ ((row & 7) << 4))) = kpre[i];
    }
#pragma unroll
    for (int i = 0; i < 4; i++) {
      const int row = vrow + i * 32;
      *(bf16x8*)(Vs + row * 128 + ((vsl * 16) ^ ((row & 7) << 4))) = vpre[i];
    }
  };

  for (int phase = 0; phase < 2; phase++) {
    const int qtile = phase ? (15 - pair) : pair;
    const int q0 = qtile * QBLK;
    const int wq = q0 + w * 32;  // this wave's first q row

    // Q -> registers (B-operand layout), RoPE + scale fused
    bf16x8 qreg[2][4];
#pragma unroll
    for (int qt = 0; qt < 2; qt++) {
      const int s = wq + qt * 16 + lr;  // sequence position (< S_)
#pragma unroll
      for (int kk = 0; kk < 4; kk++) {
        bf16x8 v = *(const bf16x8*)&QKV[((size_t)b * S_ + s) * QKVN +
                                        h * HD_ + kk * 32 + lg * 8];
        f32x4 c4 = *(const f32x4*)(cosT + (size_t)s * 64 + kk * 16 + lg * 4);
        f32x4 s4 = *(const f32x4*)(sinT + (size_t)s * 64 + kk * 16 + lg * 4);
        bf16x8 o;
#pragma unroll
        for (int j = 0; j < 4; j++) {
          float re = (float)v[2 * j], im = (float)v[2 * j + 1];
          o[2 * j]     = (bf16_t)((re * c4[j] - im * s4[j]) * scale);
          o[2 * j + 1] = (bf16_t)((re * s4[j] + im * c4[j]) * scale);
        }
        qreg[qt][kk] = o;
      }
    }

    float mrun[2] = {-INFINITY, -INFINITY};
    float lrun[2] = {0.f, 0.f};
    f32x4 acc[2][8];
    const f32x4 zero = {0.f, 0.f, 0.f, 0.f};
#pragma unroll
    for (int qt = 0; qt < 2; qt++)
#pragma unroll
      for (int d = 0; d < 8; d++) acc[qt][d] = zero;

    const int nkb = (q0 + QBLK) >> 6;
    loadKV(0);  // prologue: tile 0 into regs
    for (int kb = 0; kb < nkb; kb++) {
      const int t0 = kb * KVBLK;
      __syncthreads();              // previous tile's LDS readers done
      writeKV();                    // regs -> LDS (vmcnt wait auto-inserted)
      if (kb + 1 < nkb) loadKV(t0 + KVBLK);  // issue next tile's loads (hide under compute)
      __syncthreads();

      if (t0 > wq + 31) continue;  // causal: wave has no work this tile

      // ---- S^T = K @ Q^T : st[n][qt][r] = S[key=t0+n*16+lg*4+r][q=wq+qt*16+lr] ----
      f32x4 st[4][2];
#pragma unroll
      for (int n = 0; n < 4; n++) { st[n][0] = zero; st[n][1] = zero; }
#pragma unroll
      for (int kk = 0; kk < 4; kk++) {
        const int colb = (kk * 64 + lg * 16) ^ xm;
#pragma unroll
        for (int n = 0; n < 4; n++) {
          const bf16x8 ak = *(const bf16x8*)(Ks + (n * 16 + lr) * 256 + colb);
          st[n][0] = __builtin_amdgcn_mfma_f32_16x16x32_bf16(ak, qreg[0][kk], st[n][0], 0, 0, 0);
          st[n][1] = __builtin_amdgcn_mfma_f32_16x16x32_bf16(ak, qreg[1][kk], st[n][1], 0, 0, 0);
        }
      }

      // ---- online softmax with defer-max (T13): q = wq + qt*16 + lr, keys in-lane ----
      const bool needmask = (t0 + KVBLK - 1 > wq);
#pragma unroll
      for (int qt = 0; qt < 2; qt++) {
        const int q = wq + qt * 16 + lr;
        if (needmask) {
#pragma unroll
          for (int n = 0; n < 4; n++)
#pragma unroll
            for (int r = 0; r < 4; r++)
              if (t0 + n * 16 + lg * 4 + r > q) st[n][qt][r] = -INFINITY;
        }
        float mx = -INFINITY;
#pragma unroll
        for (int n = 0; n < 4; n++)
#pragma unroll
          for (int r = 0; r < 4; r++) mx = fmaxf(mx, st[n][qt][r]);
        mx = fmaxf(mx, __shfl_xor(mx, 16));
        mx = fmaxf(mx, __shfl_xor(mx, 32));

        const bool nore = __all(mx <= mrun[qt] + 8.0f);  // defer rescale (P bounded by e^8)
        float mnew, corr;
        if (nore) {
          mnew = mrun[qt];
        } else {
          mnew = fmaxf(mrun[qt], mx);
          corr = __expf(mrun[qt] - mnew);
        }
        float sum = 0.f;
        bf16x4 pk[4];
#pragma unroll
        for (int n = 0; n < 4; n++) {
#pragma unroll
          for (int r = 0; r < 4; r++) {
            const float p = __expf(st[n][qt][r] - mnew);
            sum += p;
            pk[n][r] = (bf16_t)p;
          }
        }
        sum += __shfl_xor(sum, 16);
        sum += __shfl_xor(sum, 32);
        if (nore) {
          lrun[qt] += sum;
        } else {
          lrun[qt] = lrun[qt] * corr + sum;
          mrun[qt] = mnew;
#pragma unroll
          for (int r = 0; r < 4; r++) {
            const float cb = __shfl(corr, lg * 4 + r);
#pragma unroll
            for (int db = 0; db < 8; db++) acc[qt][db][r] *= cb;
          }
        }
        // P^T -> P: lane writes its 4-key packs for its q-column
        {
          char* pbase = Ps + (qt * 16 + lr) * 128;
#pragma unroll
          for (int n = 0; n < 4; n++)
            *(bf16x4*)(pbase + ((n * 32 + lg * 8) ^ xm)) = pk[n];
        }
      }

      // ---- O += P @ V  (Ps is per-wave: no barrier needed) ----
#pragma unroll
      for (int kk = 0; kk < 2; kk++) {
        const int colb = (kk * 64 + lg * 16) ^ xm;
        const bf16x8 ap0 = *(const bf16x8*)(Ps + lr * 128 + colb);
        const bf16x8 ap1 = *(const bf16x8*)(Ps + (16 + lr) * 128 + colb);
#pragma unroll
        for (int db = 0; db < 8; db++) {
          const bf16x8 bv = *(const bf16x8*)(Vs + (db * 16 + lr) * 128 + colb);
          acc[0][db] = __builtin_amdgcn_mfma_f32_16x16x32_bf16(ap0, bv, acc[0][db], 0, 0, 0);
          acc[1][db] = __builtin_amdgcn_mfma_f32_16x16x32_bf16(ap1, bv, acc[1][db], 0, 0, 0);
        }
      }
    }

    // ---- epilogue: O = acc / l ----
#pragma unroll
    for (int qt = 0; qt < 2; qt++) {
      const float linv = 1.f / lrun[qt];
#pragma unroll
      for (int r = 0; r < 4; r++) {
        const float li = __shfl(linv, lg * 4 + r);
        const int q = wq + qt * 16 + lg * 4 + r;
#pragma unroll
        for (int db = 0; db < 8; db++)
          O[(((size_t)b * S_ + q) * NH_ + h) * HD_ + db * 16 + lr] = (bf16_t)(acc[qt][db][r] * li);
      }
    }
    __syncthreads();  // protect LDS before next phase restages
  }
}

extern "C" void kernel_launch(void* const* d_in, const int* in_sizes, int n_in,
                              void* d_out, int out_size, void* d_ws, size_t ws_size,
                              hipStream_t stream) {
  const float* x    = (const float*)d_in[0];
  const float* fcos = (const float*)d_in[1];
  const float* fsin = (const float*)d_in[2];
  const float* wq   = (const float*)d_in[3];
  const float* wk   = (const float*)d_in[4];
  const float* wv   = (const float*)d_in[5];
  const float* wo   = (const float*)d_in[6];
  float* out = (float*)d_out;

  char* ws = (char*)d_ws;
  bf16_t* x_bf   = (bf16_t*)(ws);               // 33.5 MB  (4096x4096 bf16)
  bf16_t* wqkvT  = (bf16_t*)(ws + 33554432);    // 50.3 MB  (6144x4096 bf16; later wo^T)
  bf16_t* qkv    = (bf16_t*)(ws + 83886080);    // 50.3 MB  (4096x6144 bf16)
  bf16_t* vt     = (bf16_t*)(ws + 134217728);   // 8.4 MB   (B,NKV,HD,S)
  bf16_t* attn   = (bf16_t*)(ws + 142606336);   // 33.5 MB  (4096x4096 bf16) end ~176 MB

  hipFuncSetAttribute(reinterpret_cast<const void*>(gemm8p<bf16_t>),
                      hipFuncAttributeMaxDynamicSharedMemorySize, 131072);
  hipFuncSetAttribute(reinterpret_cast<const void*>(gemm8p<float>),
                      hipFuncAttributeMaxDynamicSharedMemorySize, 131072);

  // 1. convert x to bf16
  convert_f32_bf16<<<8192, 256, 0, stream>>>(x, x_bf, (size_t)2097152);
  // 2. transpose+convert weights into fused (6144,4096) bf16 W^T
  transpose_convert<<<dim3(128, 128), 256, 0, stream>>>(wq, wqkvT, 4096, 4096);
  transpose_convert<<<dim3(32, 128), 256, 0, stream>>>(wk, wqkvT + (size_t)4096 * 4096, 4096, 1024);
  transpose_convert<<<dim3(32, 128), 256, 0, stream>>>(wv, wqkvT + (size_t)5120 * 4096, 4096, 1024);
  // 3. fused QKV projection: (4096,6144) bf16
  gemm8p<bf16_t><<<dim3(24, 16), 512, 131072, stream>>>(x_bf, wqkvT, qkv, 4096, QKVN, 4096);
  // 4. RoPE in-place on k only (q-rope fused into flash)
  rope_inplace<<<2048, 256, 0, stream>>>(qkv + 4096, fcos, fsin, 3, (size_t)524288);
  // 5. V -> (B,NKV,HD,S)
  transpose_v<<<dim3(64, 4, 16), 256, 0, stream>>>(qkv, vt);
  // 6. wo^T into the wqkvT slab (QKV GEMM done reading it)
  transpose_convert<<<dim3(128, 128), 256, 0, stream>>>(wo, wqkvT, 4096, 4096);
  // 7. flash attention v4 (balanced pairs, fused Q-rope, T14 async stage, T13 defer-max)
  flash_attn4<<<dim3(8, 32, 2), 256, 0, stream>>>(qkv, vt, fcos, fsin, attn);
  // 8. output projection (f32 out)
  gemm8p<float><<<dim3(16, 16), 512, 131072, stream>>>(attn, wqkvT, out, 4096, 4096, 4096);
}